// Round 3
// baseline (266.800 us; speedup 1.0000x reference)
//
#include <hip/hip_runtime.h>

// GlobalChannelAttention: B=16, C=256, H*W=4096
//
// Pipeline (TN-form GEMMs: C[M,N] = sum_k A[m][k]*B[n][k], K contiguous):
//   1. prep_w: w1 -> W1Th (bf16 transposed), w2/w3 -> hi/lo bf16, zero xsum
//   2. gram: G[b] = X X^T from raw x f32 (hi/lo in SEPARATE LDS slabs, 3
//      MFMAs hh+hl+lh). HALF-M blocks: grid 16b x 16splits x 2mhalf, each
//      512-thr block computes 128x256 over k-chunk 256, wave tiles 64x64 ->
//      acc 4x4 (64 VGPR) so A/B fragments stay hoisted in registers.
//      Per-row xsum accumulated during staging (mh==0 blocks only).
//   3. reduce_g: sum 16 partials -> Gh/Gl bf16 (float4-vectorized stream).
//      T3 = W3*G (G symmetric), Lt = T3*W2^T == logits TRANSPOSED (Lt[d][a]).
//   4. global softmax: pass1 block partials; pass3 combine + write WT bf16
//      + fused bb[d] = sum_c WT[d][c]*b1[c].
//   5. Mh = WT*W1T (bf16); out = Mh*X^T + bb, B straight from x f32 with
//      in-LDS transpose (pair-packed b32, XOR swizzle), 256x128 tiles,
//      512-thr blocks (8 waves) -> 2 blocks/CU = 4 waves/SIMD.
//
// Precision: logit chain bf16 hi/lo x3 (err ~2^-17 rel); out chain plain bf16.
// R7: atomic-f32 Gram epilogue regressed (16-way same-address L2 contention).
// R8: k-interleaved hi/lo loses hi*lo cross terms -> accuracy fail.
// R9: 128-VGPR acc forced fragment rematerialization -> LDS-read bound;
//     half-M tiles (64-VGPR acc) let fragments stay resident.
// R10: separate xsum_kernel re-read 64MB of x -- folded back into gram here.
// R11: gram latency-bound (occ 15%) -> 16 k-splits, 64KiB LDS XOR-swizzle,
//     v_cvt_pk_bf16_f32 staging, reg-prefetch k-loops. gram left top-5.
// R12: gemm_out was latency-bound (occ 17%, Mfma 6%, HBM 40%, 2 waves/SIMD)
//     -> 512-thr blocks 256x128 tile, launch_bounds(512,4) = 4 waves/SIMD at
//     same 30KB LDS. reduce_g float4-vectorized (was scalar 4B/lane, 64MB).
// R13 (this round): R12 bench never ran (container infra failure, no
//     counters). Code audit found no OOB/hang hazard; resubmitting R12
//     unchanged for a clean measurement.

typedef unsigned short u16;
typedef __attribute__((ext_vector_type(8))) short short8;
typedef __attribute__((ext_vector_type(4))) float floatx4;

__device__ __forceinline__ u16 f2b(float f) {
  union { float f; unsigned int u; } v; v.f = f;
  unsigned int u = v.u;
  return (u16)((u + 0x7fffu + ((u >> 16) & 1u)) >> 16);  // RNE
}
__device__ __forceinline__ float b2f(u16 h) {
  union { unsigned int u; float f; } v; v.u = ((unsigned int)h) << 16;
  return v.f;
}
// HW packed f32->bf16 (RNE), lo -> bits[15:0], hi -> bits[31:16].
__device__ __forceinline__ unsigned int cvt_pk_bf16(float lo, float hi) {
  unsigned int r;
  asm("v_cvt_pk_bf16_f32 %0, %1, %2" : "=v"(r) : "v"(lo), "v"(hi));
  return r;
}

// ------- merged W prep: transpose w1 + split w2/w3 + zero xsum -------------
__global__ __launch_bounds__(256) void prep_w_kernel(
    const float* __restrict__ w1, const float* __restrict__ w2, const float* __restrict__ w3,
    u16* __restrict__ W1Th, u16* __restrict__ W2h, u16* __restrict__ W2l,
    u16* __restrict__ W3h, u16* __restrict__ W3l, float* __restrict__ xsum) {
  const int blk = blockIdx.x, t = threadIdx.x;
  if (blk == 576) {  // zero xsum (16*256 f32)
#pragma unroll
    for (int i = 0; i < 16; ++i) xsum[t + i * 256] = 0.f;
    return;
  }
  if (blk < 64) {  // W1Th[e][c] = w1[c][e]
    __shared__ float tile[32][33];
    const int e0 = (blk & 7) * 32, c0 = (blk >> 3) * 32;
    const int tx = t & 31, ty = t >> 5;
#pragma unroll
    for (int i = 0; i < 4; ++i)
      tile[ty + i * 8][tx] = w1[(c0 + ty + i * 8) * 256 + e0 + tx];
    __syncthreads();
#pragma unroll
    for (int i = 0; i < 4; ++i)
      W1Th[(e0 + ty + i * 8) * 256 + c0 + tx] = f2b(tile[tx][ty + i * 8]);
  } else {
    const int i = (blk - 64) * 256 + t;  // 0..131071
    const int e = i & 0xffff;
    const float f = (i >> 16) ? w3[e] : w2[e];
    u16 h = f2b(f);
    if (i >> 16) { W3h[e] = h; W3l[e] = f2b(f - b2f(h)); }
    else         { W2h[e] = h; W2l[e] = f2b(f - b2f(h)); }
  }
}

// ---- stage 8 f32 -> hi/lo bf16 LDS (one uint4 each) + running sum --------
// Uses v_cvt_pk_bf16_f32: hi pair in 1 inst (already packed), lo pair in 1.
__device__ __forceinline__ void stage8(const float4 a, const float4 b,
                                       u16* dH, u16* dL, float& xa) {
  const float f[8] = {a.x, a.y, a.z, a.w, b.x, b.y, b.z, b.w};
  union { unsigned int w[4]; uint4 q; } uh, ul;
#pragma unroll
  for (int i = 0; i < 4; ++i) {
    const unsigned int h = cvt_pk_bf16(f[2 * i], f[2 * i + 1]);
    uh.w[i] = h;
    union { unsigned int u; float ff; } h0, h1;
    h0.u = h << 16;            // bf16 of f[2i] back to f32
    h1.u = h & 0xffff0000u;    // bf16 of f[2i+1] back to f32
    ul.w[i] = cvt_pk_bf16(f[2 * i] - h0.ff, f[2 * i + 1] - h1.ff);
    xa += f[2 * i] + f[2 * i + 1];
  }
  *(uint4*)dH = uh.q;
  *(uint4*)dL = ul.q;
}

// ---------------- Gram: half-M blocks, hoisted fragments -------------------
// grid = 16b x 16s x 2mh (blockIdx.x = b*32 + s*2 + mh). 512 thr / 8 waves,
// wave tile 64x64 (wml in {0,64}+mh*128, wn in {0,64,128,192}), k-chunk 256.
// LDS layout: row r (256 rows) = 64B = 4x 16B slots; data for k-subchunk q
// lives in slot q ^ ((r>>1)&3). Read slot for a fragment reduces to the
// per-thread constant quad ^ ((l16>>1)&3) (row low bits cancel). Both read
// and write phases are exactly 2-way on banks (free, m136). 64 KiB total ->
// 2 blocks/CU (4 waves/SIMD).
__global__ __launch_bounds__(512, 4) void gram_kernel(
    const float* __restrict__ x, float* __restrict__ Gp, float* __restrict__ xsum) {
  __shared__ u16 lH[2][256 * 32], lL[2][256 * 32];  // 64 KB total
  const int b = blockIdx.x >> 5, s = (blockIdx.x >> 1) & 15, mh = blockIdx.x & 1;
  const float* Xb = x + (long)b * 1048576 + s * 256;
  const int t = threadIdx.x;
  const int lane = t & 63, wave = t >> 6;
  const int quad = lane >> 4, l16 = lane & 15;
  const int wml = (wave & 1) * 64 + mh * 128;  // A rows in slab
  const int wn = (wave >> 1) * 64;             // B rows
  const int r0 = t >> 2, qc = (t & 3) * 8;
  const int r1 = r0 + 128;                     // (r1>>1)&3 == (r0>>1)&3
  const int wq = (((t & 3) ^ ((r0 >> 1) & 3))) * 8;  // swizzled write slot
  const int rq = ((quad ^ ((l16 >> 1) & 3))) * 8;    // swizzled read slot
  floatx4 acc[4][4] = {};
  float xa0 = 0.f, xa1 = 0.f;  // per-row running sums (rows r0, r1)
  float4 p[4];
  p[0] = *(const float4*)(Xb + (long)r0 * 4096 + qc);
  p[1] = *(const float4*)(Xb + (long)r0 * 4096 + qc + 4);
  p[2] = *(const float4*)(Xb + (long)r1 * 4096 + qc);
  p[3] = *(const float4*)(Xb + (long)r1 * 4096 + qc + 4);
  stage8(p[0], p[1], lH[0] + r0 * 32 + wq, lL[0] + r0 * 32 + wq, xa0);
  stage8(p[2], p[3], lH[0] + r1 * 32 + wq, lL[0] + r1 * 32 + wq, xa1);
  __syncthreads();
  for (int kb = 0; kb < 8; ++kb) {
    const int cur = kb & 1, nxt = cur ^ 1;
    if (kb < 7) {  // issue next tile's loads; waitcnt lands after MFMA block
      const long kk = (kb + 1) * 32;
      p[0] = *(const float4*)(Xb + (long)r0 * 4096 + kk + qc);
      p[1] = *(const float4*)(Xb + (long)r0 * 4096 + kk + qc + 4);
      p[2] = *(const float4*)(Xb + (long)r1 * 4096 + kk + qc);
      p[3] = *(const float4*)(Xb + (long)r1 * 4096 + kk + qc + 4);
    }
    const u16* cH = lH[cur];
    const u16* cL = lL[cur];
    short8 ah[4], al[4];
#pragma unroll
    for (int i = 0; i < 4; ++i) {
      ah[i] = *(const short8*)(cH + (wml + i * 16 + l16) * 32 + rq);
      al[i] = *(const short8*)(cL + (wml + i * 16 + l16) * 32 + rq);
    }
#pragma unroll
    for (int j = 0; j < 4; ++j) {
      const short8 bh = *(const short8*)(cH + (wn + j * 16 + l16) * 32 + rq);
      const short8 bl = *(const short8*)(cL + (wn + j * 16 + l16) * 32 + rq);
#pragma unroll
      for (int i = 0; i < 4; ++i) {
        acc[i][j] = __builtin_amdgcn_mfma_f32_16x16x32_bf16(ah[i], bh, acc[i][j], 0, 0, 0);
        acc[i][j] = __builtin_amdgcn_mfma_f32_16x16x32_bf16(ah[i], bl, acc[i][j], 0, 0, 0);
        acc[i][j] = __builtin_amdgcn_mfma_f32_16x16x32_bf16(al[i], bh, acc[i][j], 0, 0, 0);
      }
    }
    if (kb < 7) {
      stage8(p[0], p[1], lH[nxt] + r0 * 32 + wq, lL[nxt] + r0 * 32 + wq, xa0);
      stage8(p[2], p[3], lH[nxt] + r1 * 32 + wq, lL[nxt] + r1 * 32 + wq, xa1);
    }
    __syncthreads();
  }
  // xsum: only mh==0 contributes (both m-halves staged the same slab).
  // Threads 4k..4k+3 share rows r0/r1 -> quad shuffle then one atomic.
  if (mh == 0) {
    float v = xa0;
    v += __shfl_xor(v, 1);
    v += __shfl_xor(v, 2);
    if ((t & 3) == 0) atomicAdd(&xsum[b * 256 + r0], v);
    v = xa1;
    v += __shfl_xor(v, 1);
    v += __shfl_xor(v, 2);
    if ((t & 3) == 0) atomicAdd(&xsum[b * 256 + r1], v);
  }
  float* G = Gp + ((long)b * 16 + s) * 65536;
#pragma unroll
  for (int i = 0; i < 4; ++i) {
    const int row0 = wml + i * 16 + quad * 4;
#pragma unroll
    for (int j = 0; j < 4; ++j) {
      const int col = wn + j * 16 + l16;
#pragma unroll
      for (int r = 0; r < 4; ++r)
        G[(long)(row0 + r) * 256 + col] = acc[i][j][r];
    }
  }
}

// ------ Gram split-K reduction + hi/lo split (16 splits, float4 stream) ----
// 4 consecutive elements per thread; same i=0..15 summation order as before
// (bitwise-identical output). 1024 blocks x 256 thr covers 16*65536 elems.
__global__ __launch_bounds__(256) void reduce_g_kernel(
    const float* __restrict__ Gp, u16* __restrict__ Gh, u16* __restrict__ Gl) {
  const long e = ((long)blockIdx.x * 256 + threadIdx.x) * 4;  // elem base
  const long base = ((e >> 16) << 20) + (e & 65535);          // b*16*65536 + idx
  float4 s = {0.f, 0.f, 0.f, 0.f};
#pragma unroll
  for (int i = 0; i < 16; ++i) {
    const float4 v = *(const float4*)(Gp + base + (long)i * 65536);
    s.x += v.x; s.y += v.y; s.z += v.z; s.w += v.w;
  }
  union { u16 h[4]; uint2 q; } oh, ol;
  const float sv[4] = {s.x, s.y, s.z, s.w};
#pragma unroll
  for (int c = 0; c < 4; ++c) {
    const u16 h = f2b(sv[c]);
    oh.h[c] = h;
    ol.h[c] = f2b(sv[c] - b2f(h));
  }
  *(uint2*)(Gh + e) = oh.q;
  *(uint2*)(Gl + e) = ol.q;
}

// ------- small 256x256x256 TN GEMM: 64x64 tiles, 256-block grid ------------
// EPI: 0 = f32 store, 1 = bf16 hi/lo store, 2 = bf16 hi store
template <bool X3, int EPI>
__global__ __launch_bounds__(256) void gemm_small(
    const u16* __restrict__ Ah, const u16* __restrict__ Al,
    const u16* __restrict__ Bh, const u16* __restrict__ Bl,
    long aBatch, long bBatch, long oBatch,
    float* __restrict__ outF, u16* __restrict__ outH, u16* __restrict__ outL) {
  constexpr int LR = 40;
  __shared__ u16 smem[(X3 ? 4 : 2) * 64 * LR];
  u16* lAh = smem;
  u16* lBh = smem + 64 * LR;
  u16* lAl = X3 ? (smem + 2 * 64 * LR) : nullptr;
  u16* lBl = X3 ? (smem + 3 * 64 * LR) : nullptr;
  const int b = blockIdx.z;
  const int tm = blockIdx.x & 3, tn = blockIdx.x >> 2;  // 4x4 tiles of 64
  const u16* Ahb = Ah + (long)b * aBatch + (long)tm * 64 * 256;
  const u16* Bhb = Bh + (long)b * bBatch + (long)tn * 64 * 256;
  const u16* Alb = X3 ? (Al + (long)b * aBatch + (long)tm * 64 * 256) : nullptr;
  const u16* Blb = X3 ? (Bl + (long)b * bBatch + (long)tn * 64 * 256) : nullptr;
  const int t = threadIdx.x;
  const int lane = t & 63, wave = t >> 6;
  const int quad = lane >> 4, l16 = lane & 15;
  const int wm = (wave & 1) * 32, wn = (wave >> 1) * 32;
  const int r = t >> 2, qc = (t & 3) * 8;
  floatx4 acc[2][2] = {};
  uint4 pA, pB, pAl = {}, pBl = {};
  pA = *(const uint4*)(Ahb + (long)r * 256 + qc);
  pB = *(const uint4*)(Bhb + (long)r * 256 + qc);
  if (X3) {
    pAl = *(const uint4*)(Alb + (long)r * 256 + qc);
    pBl = *(const uint4*)(Blb + (long)r * 256 + qc);
  }
  for (int kk = 0; kk < 256; kk += 32) {
    __syncthreads();
    *(uint4*)(lAh + r * LR + qc) = pA;
    *(uint4*)(lBh + r * LR + qc) = pB;
    if (X3) {
      *(uint4*)(lAl + r * LR + qc) = pAl;
      *(uint4*)(lBl + r * LR + qc) = pBl;
    }
    __syncthreads();
    if (kk < 224) {  // prefetch next k-step; overlaps MFMA below
      pA = *(const uint4*)(Ahb + (long)r * 256 + kk + 32 + qc);
      pB = *(const uint4*)(Bhb + (long)r * 256 + kk + 32 + qc);
      if (X3) {
        pAl = *(const uint4*)(Alb + (long)r * 256 + kk + 32 + qc);
        pBl = *(const uint4*)(Blb + (long)r * 256 + kk + 32 + qc);
      }
    }
    short8 afh[2], bfh[2], afl[2], bfl[2];
#pragma unroll
    for (int i = 0; i < 2; ++i) {
      afh[i] = *(const short8*)(lAh + (wm + i * 16 + l16) * LR + quad * 8);
      bfh[i] = *(const short8*)(lBh + (wn + i * 16 + l16) * LR + quad * 8);
      if (X3) {
        afl[i] = *(const short8*)(lAl + (wm + i * 16 + l16) * LR + quad * 8);
        bfl[i] = *(const short8*)(lBl + (wn + i * 16 + l16) * LR + quad * 8);
      }
    }
#pragma unroll
    for (int i = 0; i < 2; ++i)
#pragma unroll
      for (int j = 0; j < 2; ++j) {
        acc[i][j] = __builtin_amdgcn_mfma_f32_16x16x32_bf16(afh[i], bfh[j], acc[i][j], 0, 0, 0);
        if (X3) {
          acc[i][j] = __builtin_amdgcn_mfma_f32_16x16x32_bf16(afh[i], bfl[j], acc[i][j], 0, 0, 0);
          acc[i][j] = __builtin_amdgcn_mfma_f32_16x16x32_bf16(afl[i], bfh[j], acc[i][j], 0, 0, 0);
        }
      }
  }
  const long obase = (long)b * oBatch;
#pragma unroll
  for (int i = 0; i < 2; ++i) {
    const int mb = tm * 64 + wm + i * 16 + quad * 4;
#pragma unroll
    for (int j = 0; j < 2; ++j) {
      const int n = tn * 64 + wn + j * 16 + l16;
#pragma unroll
      for (int rr = 0; rr < 4; ++rr) {
        const float v = acc[i][j][rr];
        const long idx = obase + (long)(mb + rr) * 256 + n;
        if (EPI == 0) {
          outF[idx] = v;
        } else if (EPI == 1) {
          u16 h = f2b(v);
          outH[idx] = h;
          outL[idx] = f2b(v - b2f(h));
        } else {
          outH[idx] = f2b(v);
        }
      }
    }
  }
}

// ------------- out = Mh * X^T + bb : 256x128 per block, 8 waves ------------
// 512 thr -> 2 blocks/CU (launch_bounds(512,4)) = 4 waves/SIMD. Wave grid
// 4m x 2n of 64x64 tiles, acc 4x4. B (x) pair-packed b32 with XOR swizzle.
__global__ __launch_bounds__(512, 4) void gemm_out(
    const u16* __restrict__ Mh, const float* __restrict__ x,
    const float* __restrict__ bb, float* __restrict__ out) {
  constexpr int LR = 40;
  __shared__ u16 lA[256 * LR], lB[128 * LR];  // 20 KB + 10 KB
  const int b = blockIdx.z;
  const int tn = blockIdx.x;  // 0..31
  const u16* Ab = Mh + (long)b * 65536;
  const float* Xb = x + (long)b * 1048576 + tn * 128;
  const int t = threadIdx.x;
  const int lane = t & 63, wave = t >> 6;
  const int quad = lane >> 4, l16 = lane & 15;
  const int wm = (wave & 3) * 64;     // 4 m-waves
  const int wn = (wave >> 2) * 64;    // 2 n-waves
  const int erp = (t >> 5) * 2;       // e-row pair base 0..30
  const int n0 = (t & 31) * 4;        // n offset (4 cols/thread)
  const int ra = t >> 2, qc = (t & 3) * 8;  // A staging row/col
  floatx4 acc[4][4] = {};
  uint4 pA[2];
  float4 pb0, pb1;
#pragma unroll
  for (int h = 0; h < 2; ++h)
    pA[h] = *(const uint4*)(Ab + (long)(ra + h * 128) * 256 + qc);
  pb0 = *(const float4*)(Xb + (long)erp * 4096 + n0);
  pb1 = *(const float4*)(Xb + (long)(erp + 1) * 4096 + n0);
  for (int kk = 0; kk < 256; kk += 32) {
    __syncthreads();
#pragma unroll
    for (int h = 0; h < 2; ++h)
      *(uint4*)(lA + (ra + h * 128) * LR + qc) = pA[h];
    {
      const float fa[4] = {pb0.x, pb0.y, pb0.z, pb0.w};
      const float fc[4] = {pb1.x, pb1.y, pb1.z, pb1.w};
#pragma unroll
      for (int i = 0; i < 4; ++i) {
        const int nl = n0 + i;
        const int sb = (erp >> 3) ^ ((nl >> 4) & 3);  // swizzle e-block
        *(unsigned int*)(lB + nl * LR + sb * 8 + (erp & 7)) =
            cvt_pk_bf16(fa[i], fc[i]);
      }
    }
    __syncthreads();
    if (kk < 224) {  // prefetch next k-step; overlaps MFMA below
      const int k2 = kk + 32;
#pragma unroll
      for (int h = 0; h < 2; ++h)
        pA[h] = *(const uint4*)(Ab + (long)(ra + h * 128) * 256 + k2 + qc);
      pb0 = *(const float4*)(Xb + (long)(k2 + erp) * 4096 + n0);
      pb1 = *(const float4*)(Xb + (long)(k2 + erp + 1) * 4096 + n0);
    }
    short8 af[4], bf[4];
#pragma unroll
    for (int j = 0; j < 4; ++j) {
      const int n = wn + j * 16 + l16;
      const int rb = quad ^ ((n >> 4) & 3);
      bf[j] = *(const short8*)(lB + n * LR + rb * 8);
    }
#pragma unroll
    for (int i = 0; i < 4; ++i)
      af[i] = *(const short8*)(lA + (wm + i * 16 + l16) * LR + quad * 8);
#pragma unroll
    for (int i = 0; i < 4; ++i)
#pragma unroll
      for (int j = 0; j < 4; ++j)
        acc[i][j] = __builtin_amdgcn_mfma_f32_16x16x32_bf16(af[i], bf[j], acc[i][j], 0, 0, 0);
  }
  const long obase = (long)b * 1048576;
#pragma unroll
  for (int i = 0; i < 4; ++i) {
    const int mb = wm + i * 16 + quad * 4;
#pragma unroll
    for (int j = 0; j < 4; ++j) {
      const int n = tn * 128 + wn + j * 16 + l16;
#pragma unroll
      for (int r = 0; r < 4; ++r)
        out[obase + (long)(mb + r) * 4096 + n] = acc[i][j][r] + bb[b * 256 + mb + r];
    }
  }
}

// ---------------- bias prep: s2[b][a]=w2[a,:]·xsum[b], s3 likewise --------
__global__ __launch_bounds__(512) void bias_prep_kernel(
    const float* __restrict__ w2, const float* __restrict__ w3,
    const float* __restrict__ xsum, float* __restrict__ S2, float* __restrict__ S3) {
  __shared__ float xs[256];
  const int b = blockIdx.x, t = threadIdx.x;
  if (t < 256) xs[t] = xsum[b * 256 + t];
  __syncthreads();
  const float* wm = (t < 256) ? w2 : w3;
  const int a = t & 255;
  float s = 0.f;
#pragma unroll 4
  for (int c = 0; c < 256; ++c) s += wm[a * 256 + c] * xs[c];
  if (t < 256) S2[b * 256 + a] = s;
  else         S3[b * 256 + a] = s;
}

// ---------------- softmax pass1: per-block (max, sumexp) ------------------
__global__ __launch_bounds__(256) void softmax_pass1(
    const float* __restrict__ Lt, const float* __restrict__ S2, const float* __restrict__ S3,
    const float* __restrict__ b2, const float* __restrict__ b3,
    float* __restrict__ bm, float* __restrict__ bs) {
  __shared__ float ls2[256], lb2[256];
  __shared__ float redm[4], reds[4];
  const int b = blockIdx.y, blk = blockIdx.x, t = threadIdx.x;
  ls2[t] = S2[b * 256 + t];
  lb2[t] = b2[t];
  __syncthreads();
  const int fw0 = blk * 2048 + t * 8;
  const int d = fw0 >> 8, a0 = fw0 & 255;
  const float c1 = b3[d];
  const float c0 = S3[b * 256 + d] + 4096.f * c1;
  const long base = (long)b * 65536 + fw0;
  float4 v0 = *(const float4*)(Lt + base);
  float4 v1 = *(const float4*)(Lt + base + 4);
  float v[8] = {v0.x, v0.y, v0.z, v0.w, v1.x, v1.y, v1.z, v1.w};
  float m = -3.4e38f;
#pragma unroll
  for (int i = 0; i < 8; ++i) {
    v[i] += lb2[a0 + i] * c0 + c1 * ls2[a0 + i];
    m = fmaxf(m, v[i]);
  }
  for (int o = 32; o; o >>= 1) m = fmaxf(m, __shfl_xor(m, o));
  const int wid = t >> 6, lane = t & 63;
  if (lane == 0) redm[wid] = m;
  __syncthreads();
  const float bmax = fmaxf(fmaxf(redm[0], redm[1]), fmaxf(redm[2], redm[3]));
  float s = 0.f;
#pragma unroll
  for (int i = 0; i < 8; ++i) s += __expf(v[i] - bmax);
  for (int o = 32; o; o >>= 1) s += __shfl_xor(s, o);
  if (lane == 0) reds[wid] = s;
  __syncthreads();
  if (t == 0) {
    bm[b * 32 + blk] = bmax;
    bs[b * 32 + blk] = reds[0] + reds[1] + reds[2] + reds[3];
  }
}

// -- softmax pass3: inline combine + write WT bf16 + fused bb[d]=WT·b1 ------
__global__ __launch_bounds__(256) void softmax_pass3(
    const float* __restrict__ Lt, const float* __restrict__ S2, const float* __restrict__ S3,
    const float* __restrict__ b2, const float* __restrict__ b3,
    const float* __restrict__ bm, const float* __restrict__ bs,
    const float* __restrict__ b1, u16* __restrict__ WTh, float* __restrict__ bb) {
  __shared__ float ls2[256], lb2[256], lb1[256];
  __shared__ float sM, sInv;
  const int b = blockIdx.y, blk = blockIdx.x, t = threadIdx.x;
  if (t < 64) {  // combine 32 block pairs (wave 0 only)
    const float m = (t < 32) ? bm[b * 32 + t] : -3.4e38f;
    float s = (t < 32) ? bs[b * 32 + t] : 0.f;
    float M = m;
    for (int o = 32; o; o >>= 1) M = fmaxf(M, __shfl_xor(M, o));
    s *= __expf(m - M);
    for (int o = 32; o; o >>= 1) s += __shfl_xor(s, o);
    if (t == 0) { sM = M; sInv = 1.0f / s; }
  }
  ls2[t] = S2[b * 256 + t];
  lb2[t] = b2[t];
  lb1[t] = b1[t];
  __syncthreads();
  const float M = sM, inv = sInv;
  const int fw0 = blk * 2048 + t * 8;
  const int d = fw0 >> 8, a0 = fw0 & 255;
  const float c1 = b3[d];
  const float c0 = S3[b * 256 + d] + 4096.f * c1;
  const long base = (long)b * 65536 + fw0;
  float4 v0 = *(const float4*)(Lt + base);
  float4 v1 = *(const float4*)(Lt + base + 4);
  float v[8] = {v0.x, v0.y, v0.z, v0.w, v1.x, v1.y, v1.z, v1.w};
  union { u16 h[8]; uint4 q; } o;
  float bsum = 0.f;
#pragma unroll
  for (int i = 0; i < 8; ++i) {
    const float vv = v[i] + lb2[a0 + i] * c0 + c1 * ls2[a0 + i];
    const float w = __expf(vv - M) * inv;
    o.h[i] = f2b(w);
    bsum += w * lb1[a0 + i];
  }
  *(uint4*)(WTh + base) = o.q;
  // row d spans 32 consecutive threads
  for (int off = 16; off; off >>= 1) bsum += __shfl_xor(bsum, off);
  if ((t & 31) == 0) bb[b * 256 + d] = bsum;
}

extern "C" void kernel_launch(void* const* d_in, const int* in_sizes, int n_in,
                              void* d_out, int out_size, void* d_ws, size_t ws_size,
                              hipStream_t stream) {
  const float* x  = (const float*)d_in[0];
  const float* w1 = (const float*)d_in[1];
  const float* b1 = (const float*)d_in[2];
  const float* w2 = (const float*)d_in[3];
  const float* b2 = (const float*)d_in[4];
  const float* w3 = (const float*)d_in[5];
  const float* b3 = (const float*)d_in[6];
  float* out = (float*)d_out;

  char* ws = (char*)d_ws;
  size_t off = 0;
  auto alloc = [&](size_t bytes) {
    void* p = ws + off;
    off += (bytes + 255) & ~(size_t)255;
    return p;
  };
  float* Gp = (float*)alloc(16ull * 16 * 65536 * 4);   // 64 MiB split-K partials
  float* xsum = (float*)alloc(16 * 256 * 4);
  u16* Gh   = (u16*)alloc(16ull * 65536 * 2);
  u16* Gl   = (u16*)alloc(16ull * 65536 * 2);
  u16* T3h  = (u16*)alloc(16ull * 65536 * 2);
  u16* T3l  = (u16*)alloc(16ull * 65536 * 2);
  float* Lb = (float*)alloc(16ull * 65536 * 4);        // Lt[d][a]
  u16* WTh  = (u16*)alloc(16ull * 65536 * 2);
  u16* Mh   = (u16*)alloc(16ull * 65536 * 2);
  u16* W1Th = (u16*)alloc(65536 * 2);
  u16* W2h  = (u16*)alloc(65536 * 2);
  u16* W2l  = (u16*)alloc(65536 * 2);
  u16* W3h  = (u16*)alloc(65536 * 2);
  u16* W3l  = (u16*)alloc(65536 * 2);
  float* S2   = (float*)alloc(16 * 256 * 4);
  float* S3   = (float*)alloc(16 * 256 * 4);
  float* bmx  = (float*)alloc(16 * 32 * 4);
  float* bsx  = (float*)alloc(16 * 32 * 4);
  float* bb   = (float*)alloc(16 * 256 * 4);

  prep_w_kernel<<<577, 256, 0, stream>>>(w1, w2, w3, W1Th, W2h, W2l, W3h, W3l, xsum);

  // Gram partials: 16 batches x 16 splits x 2 m-halves (xsum fused, mh==0).
  gram_kernel<<<512, 512, 0, stream>>>(x, Gp, xsum);
  reduce_g_kernel<<<1024, 256, 0, stream>>>(Gp, Gh, Gl);

  // T3 = W3 * G (G symmetric -> TN ok). 64x64 tiles, 256 blocks.
  gemm_small<true, 1><<<dim3(16, 1, 16), 256, 0, stream>>>(
      W3h, W3l, Gh, Gl, 0, 65536, 65536, nullptr, T3h, T3l);
  // Lt = T3 * W2^T  ->  Lt[d][a] = logits[a][d].
  gemm_small<true, 0><<<dim3(16, 1, 16), 256, 0, stream>>>(
      T3h, T3l, W2h, W2l, 65536, 0, 65536, Lb, nullptr, nullptr);

  // softmax: bias prep + pass1 + fused combine/write/bb pass3
  bias_prep_kernel<<<16, 512, 0, stream>>>(w2, w3, xsum, S2, S3);
  softmax_pass1<<<dim3(32, 16), 256, 0, stream>>>(Lb, S2, S3, b2, b3, bmx, bsx);
  softmax_pass3<<<dim3(32, 16), 256, 0, stream>>>(Lb, S2, S3, b2, b3, bmx, bsx,
                                                  b1, WTh, bb);

  // out-chain: Mh = WT*W1T (bf16), out = Mh*X^T + bb
  gemm_small<false, 2><<<dim3(16, 1, 16), 256, 0, stream>>>(
      WTh, nullptr, W1Th, nullptr, 65536, 0, 65536, nullptr, Mh, nullptr);
  gemm_out<<<dim3(32, 1, 16), 512, 0, stream>>>(Mh, x, bb, out);
}

// Round 4
// 231.134 us; speedup vs baseline: 1.1543x; 1.1543x over previous
//
#include <hip/hip_runtime.h>

// GlobalChannelAttention: B=16, C=256, H*W=4096
//
// Pipeline (TN-form GEMMs: C[M,N] = sum_k A[m][k]*B[n][k], K contiguous):
//   1. prep_w: w1 -> W1Th (bf16 transposed), w2/w3 -> hi/lo bf16, zero xsum
//   2. gram: G[b] = X X^T from raw x f32 (hi/lo in SEPARATE LDS slabs, 3
//      MFMAs hh+hl+lh). HALF-M blocks: grid 16b x 16splits x 2mhalf, each
//      512-thr block computes 128x256 over k-chunk 256, wave tiles 64x64 ->
//      acc 4x4 (64 VGPR) so A/B fragments stay hoisted in registers.
//      Per-row xsum accumulated during staging (mh==0 blocks only).
//   3. reduce_g: sum 16 partials -> Gh/Gl bf16 (float4-vectorized stream).
//      T3 = W3*G (G symmetric), Lt = T3*W2^T == logits TRANSPOSED (Lt[d][a]).
//   4. global softmax: pass1 block partials; pass3 combine + write WT bf16
//      + fused bb[d] = sum_c WT[d][c]*b1[c].
//   5. Mh = WT*W1T (bf16); out = Mh*X^T + bb, B straight from x f32 with
//      in-LDS transpose (pair-packed b32, XOR swizzle), 256x128 tiles,
//      512-thr blocks (8 waves).
//
// Precision: logit chain bf16 hi/lo x3 (err ~2^-17 rel); out chain plain bf16.
// R7: atomic-f32 Gram epilogue regressed (16-way same-address L2 contention).
// R8: k-interleaved hi/lo loses hi*lo cross terms -> accuracy fail.
// R9: 128-VGPR acc forced fragment rematerialization -> LDS-read bound;
//     half-M tiles (64-VGPR acc) let fragments stay resident.
// R10: separate xsum_kernel re-read 64MB of x -- folded back into gram here.
// R11: gram latency-bound (occ 15%) -> 16 k-splits, 64KiB LDS XOR-swizzle,
//     v_cvt_pk_bf16_f32 staging, reg-prefetch k-loops. gram left top-5.
// R12/R13: gemm_out 512-thr + launch_bounds(512,4): REGRESSED 45->73us.
//     HIP launch_bounds arg2 = min BLOCKS/CU (CUDA semantics): 4*512thr
//     -> 64-VGPR cap -> scratch spill (+61MB WRITE, +17MB FETCH, VGPR 104->64).
// R14 (this round): gemm_out launch_bounds(512,2) (cap 128) + bf loaded
//     per-j inside MFMA loop (16->4 regs, same LDS read count). No spill
//     expected; target 3-4 waves/SIMD with clean traffic.

typedef unsigned short u16;
typedef __attribute__((ext_vector_type(8))) short short8;
typedef __attribute__((ext_vector_type(4))) float floatx4;

__device__ __forceinline__ u16 f2b(float f) {
  union { float f; unsigned int u; } v; v.f = f;
  unsigned int u = v.u;
  return (u16)((u + 0x7fffu + ((u >> 16) & 1u)) >> 16);  // RNE
}
__device__ __forceinline__ float b2f(u16 h) {
  union { unsigned int u; float f; } v; v.u = ((unsigned int)h) << 16;
  return v.f;
}
// HW packed f32->bf16 (RNE), lo -> bits[15:0], hi -> bits[31:16].
__device__ __forceinline__ unsigned int cvt_pk_bf16(float lo, float hi) {
  unsigned int r;
  asm("v_cvt_pk_bf16_f32 %0, %1, %2" : "=v"(r) : "v"(lo), "v"(hi));
  return r;
}

// ------- merged W prep: transpose w1 + split w2/w3 + zero xsum -------------
__global__ __launch_bounds__(256) void prep_w_kernel(
    const float* __restrict__ w1, const float* __restrict__ w2, const float* __restrict__ w3,
    u16* __restrict__ W1Th, u16* __restrict__ W2h, u16* __restrict__ W2l,
    u16* __restrict__ W3h, u16* __restrict__ W3l, float* __restrict__ xsum) {
  const int blk = blockIdx.x, t = threadIdx.x;
  if (blk == 576) {  // zero xsum (16*256 f32)
#pragma unroll
    for (int i = 0; i < 16; ++i) xsum[t + i * 256] = 0.f;
    return;
  }
  if (blk < 64) {  // W1Th[e][c] = w1[c][e]
    __shared__ float tile[32][33];
    const int e0 = (blk & 7) * 32, c0 = (blk >> 3) * 32;
    const int tx = t & 31, ty = t >> 5;
#pragma unroll
    for (int i = 0; i < 4; ++i)
      tile[ty + i * 8][tx] = w1[(c0 + ty + i * 8) * 256 + e0 + tx];
    __syncthreads();
#pragma unroll
    for (int i = 0; i < 4; ++i)
      W1Th[(e0 + ty + i * 8) * 256 + c0 + tx] = f2b(tile[tx][ty + i * 8]);
  } else {
    const int i = (blk - 64) * 256 + t;  // 0..131071
    const int e = i & 0xffff;
    const float f = (i >> 16) ? w3[e] : w2[e];
    u16 h = f2b(f);
    if (i >> 16) { W3h[e] = h; W3l[e] = f2b(f - b2f(h)); }
    else         { W2h[e] = h; W2l[e] = f2b(f - b2f(h)); }
  }
}

// ---- stage 8 f32 -> hi/lo bf16 LDS (one uint4 each) + running sum --------
// Uses v_cvt_pk_bf16_f32: hi pair in 1 inst (already packed), lo pair in 1.
__device__ __forceinline__ void stage8(const float4 a, const float4 b,
                                       u16* dH, u16* dL, float& xa) {
  const float f[8] = {a.x, a.y, a.z, a.w, b.x, b.y, b.z, b.w};
  union { unsigned int w[4]; uint4 q; } uh, ul;
#pragma unroll
  for (int i = 0; i < 4; ++i) {
    const unsigned int h = cvt_pk_bf16(f[2 * i], f[2 * i + 1]);
    uh.w[i] = h;
    union { unsigned int u; float ff; } h0, h1;
    h0.u = h << 16;            // bf16 of f[2i] back to f32
    h1.u = h & 0xffff0000u;    // bf16 of f[2i+1] back to f32
    ul.w[i] = cvt_pk_bf16(f[2 * i] - h0.ff, f[2 * i + 1] - h1.ff);
    xa += f[2 * i] + f[2 * i + 1];
  }
  *(uint4*)dH = uh.q;
  *(uint4*)dL = ul.q;
}

// ---------------- Gram: half-M blocks, hoisted fragments -------------------
// grid = 16b x 16s x 2mh (blockIdx.x = b*32 + s*2 + mh). 512 thr / 8 waves,
// wave tile 64x64 (wml in {0,64}+mh*128, wn in {0,64,128,192}), k-chunk 256.
// LDS layout: row r (256 rows) = 64B = 4x 16B slots; data for k-subchunk q
// lives in slot q ^ ((r>>1)&3). Read slot for a fragment reduces to the
// per-thread constant quad ^ ((l16>>1)&3) (row low bits cancel). Both read
// and write phases are exactly 2-way on banks (free, m136). 64 KiB total ->
// 2 blocks/CU (4 waves/SIMD).
__global__ __launch_bounds__(512, 4) void gram_kernel(
    const float* __restrict__ x, float* __restrict__ Gp, float* __restrict__ xsum) {
  __shared__ u16 lH[2][256 * 32], lL[2][256 * 32];  // 64 KB total
  const int b = blockIdx.x >> 5, s = (blockIdx.x >> 1) & 15, mh = blockIdx.x & 1;
  const float* Xb = x + (long)b * 1048576 + s * 256;
  const int t = threadIdx.x;
  const int lane = t & 63, wave = t >> 6;
  const int quad = lane >> 4, l16 = lane & 15;
  const int wml = (wave & 1) * 64 + mh * 128;  // A rows in slab
  const int wn = (wave >> 1) * 64;             // B rows
  const int r0 = t >> 2, qc = (t & 3) * 8;
  const int r1 = r0 + 128;                     // (r1>>1)&3 == (r0>>1)&3
  const int wq = (((t & 3) ^ ((r0 >> 1) & 3))) * 8;  // swizzled write slot
  const int rq = ((quad ^ ((l16 >> 1) & 3))) * 8;    // swizzled read slot
  floatx4 acc[4][4] = {};
  float xa0 = 0.f, xa1 = 0.f;  // per-row running sums (rows r0, r1)
  float4 p[4];
  p[0] = *(const float4*)(Xb + (long)r0 * 4096 + qc);
  p[1] = *(const float4*)(Xb + (long)r0 * 4096 + qc + 4);
  p[2] = *(const float4*)(Xb + (long)r1 * 4096 + qc);
  p[3] = *(const float4*)(Xb + (long)r1 * 4096 + qc + 4);
  stage8(p[0], p[1], lH[0] + r0 * 32 + wq, lL[0] + r0 * 32 + wq, xa0);
  stage8(p[2], p[3], lH[0] + r1 * 32 + wq, lL[0] + r1 * 32 + wq, xa1);
  __syncthreads();
  for (int kb = 0; kb < 8; ++kb) {
    const int cur = kb & 1, nxt = cur ^ 1;
    if (kb < 7) {  // issue next tile's loads; waitcnt lands after MFMA block
      const long kk = (kb + 1) * 32;
      p[0] = *(const float4*)(Xb + (long)r0 * 4096 + kk + qc);
      p[1] = *(const float4*)(Xb + (long)r0 * 4096 + kk + qc + 4);
      p[2] = *(const float4*)(Xb + (long)r1 * 4096 + kk + qc);
      p[3] = *(const float4*)(Xb + (long)r1 * 4096 + kk + qc + 4);
    }
    const u16* cH = lH[cur];
    const u16* cL = lL[cur];
    short8 ah[4], al[4];
#pragma unroll
    for (int i = 0; i < 4; ++i) {
      ah[i] = *(const short8*)(cH + (wml + i * 16 + l16) * 32 + rq);
      al[i] = *(const short8*)(cL + (wml + i * 16 + l16) * 32 + rq);
    }
#pragma unroll
    for (int j = 0; j < 4; ++j) {
      const short8 bh = *(const short8*)(cH + (wn + j * 16 + l16) * 32 + rq);
      const short8 bl = *(const short8*)(cL + (wn + j * 16 + l16) * 32 + rq);
#pragma unroll
      for (int i = 0; i < 4; ++i) {
        acc[i][j] = __builtin_amdgcn_mfma_f32_16x16x32_bf16(ah[i], bh, acc[i][j], 0, 0, 0);
        acc[i][j] = __builtin_amdgcn_mfma_f32_16x16x32_bf16(ah[i], bl, acc[i][j], 0, 0, 0);
        acc[i][j] = __builtin_amdgcn_mfma_f32_16x16x32_bf16(al[i], bh, acc[i][j], 0, 0, 0);
      }
    }
    if (kb < 7) {
      stage8(p[0], p[1], lH[nxt] + r0 * 32 + wq, lL[nxt] + r0 * 32 + wq, xa0);
      stage8(p[2], p[3], lH[nxt] + r1 * 32 + wq, lL[nxt] + r1 * 32 + wq, xa1);
    }
    __syncthreads();
  }
  // xsum: only mh==0 contributes (both m-halves staged the same slab).
  // Threads 4k..4k+3 share rows r0/r1 -> quad shuffle then one atomic.
  if (mh == 0) {
    float v = xa0;
    v += __shfl_xor(v, 1);
    v += __shfl_xor(v, 2);
    if ((t & 3) == 0) atomicAdd(&xsum[b * 256 + r0], v);
    v = xa1;
    v += __shfl_xor(v, 1);
    v += __shfl_xor(v, 2);
    if ((t & 3) == 0) atomicAdd(&xsum[b * 256 + r1], v);
  }
  float* G = Gp + ((long)b * 16 + s) * 65536;
#pragma unroll
  for (int i = 0; i < 4; ++i) {
    const int row0 = wml + i * 16 + quad * 4;
#pragma unroll
    for (int j = 0; j < 4; ++j) {
      const int col = wn + j * 16 + l16;
#pragma unroll
      for (int r = 0; r < 4; ++r)
        G[(long)(row0 + r) * 256 + col] = acc[i][j][r];
    }
  }
}

// ------ Gram split-K reduction + hi/lo split (16 splits, float4 stream) ----
// 4 consecutive elements per thread; same i=0..15 summation order as before
// (bitwise-identical output). 1024 blocks x 256 thr covers 16*65536 elems.
__global__ __launch_bounds__(256) void reduce_g_kernel(
    const float* __restrict__ Gp, u16* __restrict__ Gh, u16* __restrict__ Gl) {
  const long e = ((long)blockIdx.x * 256 + threadIdx.x) * 4;  // elem base
  const long base = ((e >> 16) << 20) + (e & 65535);          // b*16*65536 + idx
  float4 s = {0.f, 0.f, 0.f, 0.f};
#pragma unroll
  for (int i = 0; i < 16; ++i) {
    const float4 v = *(const float4*)(Gp + base + (long)i * 65536);
    s.x += v.x; s.y += v.y; s.z += v.z; s.w += v.w;
  }
  union { u16 h[4]; uint2 q; } oh, ol;
  const float sv[4] = {s.x, s.y, s.z, s.w};
#pragma unroll
  for (int c = 0; c < 4; ++c) {
    const u16 h = f2b(sv[c]);
    oh.h[c] = h;
    ol.h[c] = f2b(sv[c] - b2f(h));
  }
  *(uint2*)(Gh + e) = oh.q;
  *(uint2*)(Gl + e) = ol.q;
}

// ------- small 256x256x256 TN GEMM: 64x64 tiles, 256-block grid ------------
// EPI: 0 = f32 store, 1 = bf16 hi/lo store, 2 = bf16 hi store
template <bool X3, int EPI>
__global__ __launch_bounds__(256) void gemm_small(
    const u16* __restrict__ Ah, const u16* __restrict__ Al,
    const u16* __restrict__ Bh, const u16* __restrict__ Bl,
    long aBatch, long bBatch, long oBatch,
    float* __restrict__ outF, u16* __restrict__ outH, u16* __restrict__ outL) {
  constexpr int LR = 40;
  __shared__ u16 smem[(X3 ? 4 : 2) * 64 * LR];
  u16* lAh = smem;
  u16* lBh = smem + 64 * LR;
  u16* lAl = X3 ? (smem + 2 * 64 * LR) : nullptr;
  u16* lBl = X3 ? (smem + 3 * 64 * LR) : nullptr;
  const int b = blockIdx.z;
  const int tm = blockIdx.x & 3, tn = blockIdx.x >> 2;  // 4x4 tiles of 64
  const u16* Ahb = Ah + (long)b * aBatch + (long)tm * 64 * 256;
  const u16* Bhb = Bh + (long)b * bBatch + (long)tn * 64 * 256;
  const u16* Alb = X3 ? (Al + (long)b * aBatch + (long)tm * 64 * 256) : nullptr;
  const u16* Blb = X3 ? (Bl + (long)b * bBatch + (long)tn * 64 * 256) : nullptr;
  const int t = threadIdx.x;
  const int lane = t & 63, wave = t >> 6;
  const int quad = lane >> 4, l16 = lane & 15;
  const int wm = (wave & 1) * 32, wn = (wave >> 1) * 32;
  const int r = t >> 2, qc = (t & 3) * 8;
  floatx4 acc[2][2] = {};
  uint4 pA, pB, pAl = {}, pBl = {};
  pA = *(const uint4*)(Ahb + (long)r * 256 + qc);
  pB = *(const uint4*)(Bhb + (long)r * 256 + qc);
  if (X3) {
    pAl = *(const uint4*)(Alb + (long)r * 256 + qc);
    pBl = *(const uint4*)(Blb + (long)r * 256 + qc);
  }
  for (int kk = 0; kk < 256; kk += 32) {
    __syncthreads();
    *(uint4*)(lAh + r * LR + qc) = pA;
    *(uint4*)(lBh + r * LR + qc) = pB;
    if (X3) {
      *(uint4*)(lAl + r * LR + qc) = pAl;
      *(uint4*)(lBl + r * LR + qc) = pBl;
    }
    __syncthreads();
    if (kk < 224) {  // prefetch next k-step; overlaps MFMA below
      pA = *(const uint4*)(Ahb + (long)r * 256 + kk + 32 + qc);
      pB = *(const uint4*)(Bhb + (long)r * 256 + kk + 32 + qc);
      if (X3) {
        pAl = *(const uint4*)(Alb + (long)r * 256 + kk + 32 + qc);
        pBl = *(const uint4*)(Blb + (long)r * 256 + kk + 32 + qc);
      }
    }
    short8 afh[2], bfh[2], afl[2], bfl[2];
#pragma unroll
    for (int i = 0; i < 2; ++i) {
      afh[i] = *(const short8*)(lAh + (wm + i * 16 + l16) * LR + quad * 8);
      bfh[i] = *(const short8*)(lBh + (wn + i * 16 + l16) * LR + quad * 8);
      if (X3) {
        afl[i] = *(const short8*)(lAl + (wm + i * 16 + l16) * LR + quad * 8);
        bfl[i] = *(const short8*)(lBl + (wn + i * 16 + l16) * LR + quad * 8);
      }
    }
#pragma unroll
    for (int i = 0; i < 2; ++i)
#pragma unroll
      for (int j = 0; j < 2; ++j) {
        acc[i][j] = __builtin_amdgcn_mfma_f32_16x16x32_bf16(afh[i], bfh[j], acc[i][j], 0, 0, 0);
        if (X3) {
          acc[i][j] = __builtin_amdgcn_mfma_f32_16x16x32_bf16(afh[i], bfl[j], acc[i][j], 0, 0, 0);
          acc[i][j] = __builtin_amdgcn_mfma_f32_16x16x32_bf16(afl[i], bfh[j], acc[i][j], 0, 0, 0);
        }
      }
  }
  const long obase = (long)b * oBatch;
#pragma unroll
  for (int i = 0; i < 2; ++i) {
    const int mb = tm * 64 + wm + i * 16 + quad * 4;
#pragma unroll
    for (int j = 0; j < 2; ++j) {
      const int n = tn * 64 + wn + j * 16 + l16;
#pragma unroll
      for (int rr = 0; rr < 4; ++rr) {
        const float v = acc[i][j][rr];
        const long idx = obase + (long)(mb + rr) * 256 + n;
        if (EPI == 0) {
          outF[idx] = v;
        } else if (EPI == 1) {
          u16 h = f2b(v);
          outH[idx] = h;
          outL[idx] = f2b(v - b2f(h));
        } else {
          outH[idx] = f2b(v);
        }
      }
    }
  }
}

// ------------- out = Mh * X^T + bb : 256x128 per block, 8 waves ------------
// 512 thr, launch_bounds(512,2) -> VGPR cap 128 (HIP arg2 = min blocks/CU,
// CUDA semantics -- (512,4) capped at 64 and spilled, R12/R13). acc 4x4
// (->AGPR) + af[4] hoisted; bf loaded per-j (4 regs not 16, same LDS reads).
__global__ __launch_bounds__(512, 2) void gemm_out(
    const u16* __restrict__ Mh, const float* __restrict__ x,
    const float* __restrict__ bb, float* __restrict__ out) {
  constexpr int LR = 40;
  __shared__ u16 lA[256 * LR], lB[128 * LR];  // 20 KB + 10 KB
  const int b = blockIdx.z;
  const int tn = blockIdx.x;  // 0..31
  const u16* Ab = Mh + (long)b * 65536;
  const float* Xb = x + (long)b * 1048576 + tn * 128;
  const int t = threadIdx.x;
  const int lane = t & 63, wave = t >> 6;
  const int quad = lane >> 4, l16 = lane & 15;
  const int wm = (wave & 3) * 64;     // 4 m-waves
  const int wn = (wave >> 2) * 64;    // 2 n-waves
  const int erp = (t >> 5) * 2;       // e-row pair base 0..30
  const int n0 = (t & 31) * 4;        // n offset (4 cols/thread)
  const int ra = t >> 2, qc = (t & 3) * 8;  // A staging row/col
  floatx4 acc[4][4] = {};
  uint4 pA[2];
  float4 pb0, pb1;
#pragma unroll
  for (int h = 0; h < 2; ++h)
    pA[h] = *(const uint4*)(Ab + (long)(ra + h * 128) * 256 + qc);
  pb0 = *(const float4*)(Xb + (long)erp * 4096 + n0);
  pb1 = *(const float4*)(Xb + (long)(erp + 1) * 4096 + n0);
  for (int kk = 0; kk < 256; kk += 32) {
    __syncthreads();
#pragma unroll
    for (int h = 0; h < 2; ++h)
      *(uint4*)(lA + (ra + h * 128) * LR + qc) = pA[h];
    {
      const float fa[4] = {pb0.x, pb0.y, pb0.z, pb0.w};
      const float fc[4] = {pb1.x, pb1.y, pb1.z, pb1.w};
#pragma unroll
      for (int i = 0; i < 4; ++i) {
        const int nl = n0 + i;
        const int sb = (erp >> 3) ^ ((nl >> 4) & 3);  // swizzle e-block
        *(unsigned int*)(lB + nl * LR + sb * 8 + (erp & 7)) =
            cvt_pk_bf16(fa[i], fc[i]);
      }
    }
    __syncthreads();
    if (kk < 224) {  // prefetch next k-step; overlaps MFMA below
      const int k2 = kk + 32;
#pragma unroll
      for (int h = 0; h < 2; ++h)
        pA[h] = *(const uint4*)(Ab + (long)(ra + h * 128) * 256 + k2 + qc);
      pb0 = *(const float4*)(Xb + (long)(k2 + erp) * 4096 + n0);
      pb1 = *(const float4*)(Xb + (long)(k2 + erp + 1) * 4096 + n0);
    }
    short8 af[4];
#pragma unroll
    for (int i = 0; i < 4; ++i)
      af[i] = *(const short8*)(lA + (wm + i * 16 + l16) * LR + quad * 8);
#pragma unroll
    for (int j = 0; j < 4; ++j) {
      const int n = wn + j * 16 + l16;
      const int rb = quad ^ ((n >> 4) & 3);
      const short8 bf = *(const short8*)(lB + n * LR + rb * 8);
#pragma unroll
      for (int i = 0; i < 4; ++i)
        acc[i][j] = __builtin_amdgcn_mfma_f32_16x16x32_bf16(af[i], bf, acc[i][j], 0, 0, 0);
    }
  }
  const long obase = (long)b * 1048576;
#pragma unroll
  for (int i = 0; i < 4; ++i) {
    const int mb = wm + i * 16 + quad * 4;
#pragma unroll
    for (int j = 0; j < 4; ++j) {
      const int n = tn * 128 + wn + j * 16 + l16;
#pragma unroll
      for (int r = 0; r < 4; ++r)
        out[obase + (long)(mb + r) * 4096 + n] = acc[i][j][r] + bb[b * 256 + mb + r];
    }
  }
}

// ---------------- bias prep: s2[b][a]=w2[a,:]·xsum[b], s3 likewise --------
__global__ __launch_bounds__(512) void bias_prep_kernel(
    const float* __restrict__ w2, const float* __restrict__ w3,
    const float* __restrict__ xsum, float* __restrict__ S2, float* __restrict__ S3) {
  __shared__ float xs[256];
  const int b = blockIdx.x, t = threadIdx.x;
  if (t < 256) xs[t] = xsum[b * 256 + t];
  __syncthreads();
  const float* wm = (t < 256) ? w2 : w3;
  const int a = t & 255;
  float s = 0.f;
#pragma unroll 4
  for (int c = 0; c < 256; ++c) s += wm[a * 256 + c] * xs[c];
  if (t < 256) S2[b * 256 + a] = s;
  else         S3[b * 256 + a] = s;
}

// ---------------- softmax pass1: per-block (max, sumexp) ------------------
__global__ __launch_bounds__(256) void softmax_pass1(
    const float* __restrict__ Lt, const float* __restrict__ S2, const float* __restrict__ S3,
    const float* __restrict__ b2, const float* __restrict__ b3,
    float* __restrict__ bm, float* __restrict__ bs) {
  __shared__ float ls2[256], lb2[256];
  __shared__ float redm[4], reds[4];
  const int b = blockIdx.y, blk = blockIdx.x, t = threadIdx.x;
  ls2[t] = S2[b * 256 + t];
  lb2[t] = b2[t];
  __syncthreads();
  const int fw0 = blk * 2048 + t * 8;
  const int d = fw0 >> 8, a0 = fw0 & 255;
  const float c1 = b3[d];
  const float c0 = S3[b * 256 + d] + 4096.f * c1;
  const long base = (long)b * 65536 + fw0;
  float4 v0 = *(const float4*)(Lt + base);
  float4 v1 = *(const float4*)(Lt + base + 4);
  float v[8] = {v0.x, v0.y, v0.z, v0.w, v1.x, v1.y, v1.z, v1.w};
  float m = -3.4e38f;
#pragma unroll
  for (int i = 0; i < 8; ++i) {
    v[i] += lb2[a0 + i] * c0 + c1 * ls2[a0 + i];
    m = fmaxf(m, v[i]);
  }
  for (int o = 32; o; o >>= 1) m = fmaxf(m, __shfl_xor(m, o));
  const int wid = t >> 6, lane = t & 63;
  if (lane == 0) redm[wid] = m;
  __syncthreads();
  const float bmax = fmaxf(fmaxf(redm[0], redm[1]), fmaxf(redm[2], redm[3]));
  float s = 0.f;
#pragma unroll
  for (int i = 0; i < 8; ++i) s += __expf(v[i] - bmax);
  for (int o = 32; o; o >>= 1) s += __shfl_xor(s, o);
  if (lane == 0) reds[wid] = s;
  __syncthreads();
  if (t == 0) {
    bm[b * 32 + blk] = bmax;
    bs[b * 32 + blk] = reds[0] + reds[1] + reds[2] + reds[3];
  }
}

// -- softmax pass3: inline combine + write WT bf16 + fused bb[d]=WT·b1 ------
__global__ __launch_bounds__(256) void softmax_pass3(
    const float* __restrict__ Lt, const float* __restrict__ S2, const float* __restrict__ S3,
    const float* __restrict__ b2, const float* __restrict__ b3,
    const float* __restrict__ bm, const float* __restrict__ bs,
    const float* __restrict__ b1, u16* __restrict__ WTh, float* __restrict__ bb) {
  __shared__ float ls2[256], lb2[256], lb1[256];
  __shared__ float sM, sInv;
  const int b = blockIdx.y, blk = blockIdx.x, t = threadIdx.x;
  if (t < 64) {  // combine 32 block pairs (wave 0 only)
    const float m = (t < 32) ? bm[b * 32 + t] : -3.4e38f;
    float s = (t < 32) ? bs[b * 32 + t] : 0.f;
    float M = m;
    for (int o = 32; o; o >>= 1) M = fmaxf(M, __shfl_xor(M, o));
    s *= __expf(m - M);
    for (int o = 32; o; o >>= 1) s += __shfl_xor(s, o);
    if (t == 0) { sM = M; sInv = 1.0f / s; }
  }
  ls2[t] = S2[b * 256 + t];
  lb2[t] = b2[t];
  lb1[t] = b1[t];
  __syncthreads();
  const float M = sM, inv = sInv;
  const int fw0 = blk * 2048 + t * 8;
  const int d = fw0 >> 8, a0 = fw0 & 255;
  const float c1 = b3[d];
  const float c0 = S3[b * 256 + d] + 4096.f * c1;
  const long base = (long)b * 65536 + fw0;
  float4 v0 = *(const float4*)(Lt + base);
  float4 v1 = *(const float4*)(Lt + base + 4);
  float v[8] = {v0.x, v0.y, v0.z, v0.w, v1.x, v1.y, v1.z, v1.w};
  union { u16 h[8]; uint4 q; } o;
  float bsum = 0.f;
#pragma unroll
  for (int i = 0; i < 8; ++i) {
    const float vv = v[i] + lb2[a0 + i] * c0 + c1 * ls2[a0 + i];
    const float w = __expf(vv - M) * inv;
    o.h[i] = f2b(w);
    bsum += w * lb1[a0 + i];
  }
  *(uint4*)(WTh + base) = o.q;
  // row d spans 32 consecutive threads
  for (int off = 16; off; off >>= 1) bsum += __shfl_xor(bsum, off);
  if ((t & 31) == 0) bb[b * 256 + d] = bsum;
}

extern "C" void kernel_launch(void* const* d_in, const int* in_sizes, int n_in,
                              void* d_out, int out_size, void* d_ws, size_t ws_size,
                              hipStream_t stream) {
  const float* x  = (const float*)d_in[0];
  const float* w1 = (const float*)d_in[1];
  const float* b1 = (const float*)d_in[2];
  const float* w2 = (const float*)d_in[3];
  const float* b2 = (const float*)d_in[4];
  const float* w3 = (const float*)d_in[5];
  const float* b3 = (const float*)d_in[6];
  float* out = (float*)d_out;

  char* ws = (char*)d_ws;
  size_t off = 0;
  auto alloc = [&](size_t bytes) {
    void* p = ws + off;
    off += (bytes + 255) & ~(size_t)255;
    return p;
  };
  float* Gp = (float*)alloc(16ull * 16 * 65536 * 4);   // 64 MiB split-K partials
  float* xsum = (float*)alloc(16 * 256 * 4);
  u16* Gh   = (u16*)alloc(16ull * 65536 * 2);
  u16* Gl   = (u16*)alloc(16ull * 65536 * 2);
  u16* T3h  = (u16*)alloc(16ull * 65536 * 2);
  u16* T3l  = (u16*)alloc(16ull * 65536 * 2);
  float* Lb = (float*)alloc(16ull * 65536 * 4);        // Lt[d][a]
  u16* WTh  = (u16*)alloc(16ull * 65536 * 2);
  u16* Mh   = (u16*)alloc(16ull * 65536 * 2);
  u16* W1Th = (u16*)alloc(65536 * 2);
  u16* W2h  = (u16*)alloc(65536 * 2);
  u16* W2l  = (u16*)alloc(65536 * 2);
  u16* W3h  = (u16*)alloc(65536 * 2);
  u16* W3l  = (u16*)alloc(65536 * 2);
  float* S2   = (float*)alloc(16 * 256 * 4);
  float* S3   = (float*)alloc(16 * 256 * 4);
  float* bmx  = (float*)alloc(16 * 32 * 4);
  float* bsx  = (float*)alloc(16 * 32 * 4);
  float* bb   = (float*)alloc(16 * 256 * 4);

  prep_w_kernel<<<577, 256, 0, stream>>>(w1, w2, w3, W1Th, W2h, W2l, W3h, W3l, xsum);

  // Gram partials: 16 batches x 16 splits x 2 m-halves (xsum fused, mh==0).
  gram_kernel<<<512, 512, 0, stream>>>(x, Gp, xsum);
  reduce_g_kernel<<<1024, 256, 0, stream>>>(Gp, Gh, Gl);

  // T3 = W3 * G (G symmetric -> TN ok). 64x64 tiles, 256 blocks.
  gemm_small<true, 1><<<dim3(16, 1, 16), 256, 0, stream>>>(
      W3h, W3l, Gh, Gl, 0, 65536, 65536, nullptr, T3h, T3l);
  // Lt = T3 * W2^T  ->  Lt[d][a] = logits[a][d].
  gemm_small<true, 0><<<dim3(16, 1, 16), 256, 0, stream>>>(
      T3h, T3l, W2h, W2l, 65536, 0, 65536, Lb, nullptr, nullptr);

  // softmax: bias prep + pass1 + fused combine/write/bb pass3
  bias_prep_kernel<<<16, 512, 0, stream>>>(w2, w3, xsum, S2, S3);
  softmax_pass1<<<dim3(32, 16), 256, 0, stream>>>(Lb, S2, S3, b2, b3, bmx, bsx);
  softmax_pass3<<<dim3(32, 16), 256, 0, stream>>>(Lb, S2, S3, b2, b3, bmx, bsx,
                                                  b1, WTh, bb);

  // out-chain: Mh = WT*W1T (bf16), out = Mh*X^T + bb
  gemm_small<false, 2><<<dim3(16, 1, 16), 256, 0, stream>>>(
      WTh, nullptr, W1Th, nullptr, 65536, 0, 65536, nullptr, Mh, nullptr);
  gemm_out<<<dim3(32, 1, 16), 512, 0, stream>>>(Mh, x, bb, out);
}

// Round 5
// 218.442 us; speedup vs baseline: 1.2214x; 1.0581x over previous
//
#include <hip/hip_runtime.h>

// GlobalChannelAttention: B=16, C=256, H*W=4096
//
// Pipeline (TN-form GEMMs: C[M,N] = sum_k A[m][k]*B[n][k], K contiguous):
//   1. prep_w: w1 -> W1Th (bf16 transposed), w2/w3 -> hi/lo bf16, zero xsum
//   2. gram: G[b] = X X^T from raw x f32 (hi/lo in SEPARATE LDS slabs, 3
//      MFMAs hh+hl+lh). HALF-M blocks: grid 16b x 16splits x 2mhalf.
//   3. reduce_g: sum 16 partials -> Gh/Gl bf16 (float4-vectorized stream).
//      T3 = W3*G (G symmetric), Lt = T3*W2^T == logits TRANSPOSED (Lt[d][a]).
//   4. global softmax: pass1 block partials; pass3 combine + write WT bf16
//      + fused bb[d] = sum_c WT[d][c]*b1[c].
//   5. Mh = WT*W1T (bf16); out = Mh*X^T + bb, 256x128 tiles, 512 thr.
//
// Precision: logit chain bf16 hi/lo x3 (err ~2^-17 rel); out chain plain bf16.
// R7: atomic-f32 Gram epilogue regressed (16-way same-address L2 contention).
// R8: k-interleaved hi/lo loses hi*lo cross terms -> accuracy fail.
// R9: 128-VGPR acc forced fragment rematerialization -> LDS-read bound.
// R10: separate xsum_kernel re-read 64MB of x -- folded back into gram.
// R11: gram latency-bound -> 16 k-splits, 64KiB LDS XOR-swizzle, cvt_pk
//     staging, reg-prefetch. gram 46->41us, 0 bank conflicts (XOR verified).
// R12/R13: launch_bounds(512,4) = 4 BLOCKS/CU (CUDA semantics) -> 64-VGPR
//     cap -> scratch spill (+78MB traffic). REGRESSED 45->73us.
// R14: (512,2) + per-j bf: spill gone, 41.7us. But 76+64acc=140 regs/wave
//     -> only 3 waves/SIMD; 2.36M LDS conflicts in lB WRITE phase
//     (lane t writes nl=4t+i, bank stride 80B = 2-way).
// R15 (this round): gemm_out A-staging via global_load_lds (dbuf, LR=32,
//     gram's XOR slot; involution applied to per-lane global source col +
//     read slot -- rule "both-sides-or-neither"). lB write remap: lane t
//     writes nl=(t&31)+32i (consecutive lanes -> consecutive rows, free);
//     B loaded as 8 coalesced scalar dwords. Target <=64 arch VGPR ->
//     2 blocks/CU = 4 waves/SIMD.

typedef unsigned short u16;
typedef __attribute__((ext_vector_type(8))) short short8;
typedef __attribute__((ext_vector_type(4))) float floatx4;

__device__ __forceinline__ u16 f2b(float f) {
  union { float f; unsigned int u; } v; v.f = f;
  unsigned int u = v.u;
  return (u16)((u + 0x7fffu + ((u >> 16) & 1u)) >> 16);  // RNE
}
__device__ __forceinline__ float b2f(u16 h) {
  union { unsigned int u; float f; } v; v.u = ((unsigned int)h) << 16;
  return v.f;
}
// HW packed f32->bf16 (RNE), lo -> bits[15:0], hi -> bits[31:16].
__device__ __forceinline__ unsigned int cvt_pk_bf16(float lo, float hi) {
  unsigned int r;
  asm("v_cvt_pk_bf16_f32 %0, %1, %2" : "=v"(r) : "v"(lo), "v"(hi));
  return r;
}
// async global->LDS, 16B per lane. LDS dest = wave-uniform base + lane*16.
__device__ __forceinline__ void gload_lds16(const u16* g, u16* l) {
  __builtin_amdgcn_global_load_lds(
      (const __attribute__((address_space(1))) unsigned int*)(const void*)g,
      (__attribute__((address_space(3))) unsigned int*)(void*)l, 16, 0, 0);
}

// ------- merged W prep: transpose w1 + split w2/w3 + zero xsum -------------
__global__ __launch_bounds__(256) void prep_w_kernel(
    const float* __restrict__ w1, const float* __restrict__ w2, const float* __restrict__ w3,
    u16* __restrict__ W1Th, u16* __restrict__ W2h, u16* __restrict__ W2l,
    u16* __restrict__ W3h, u16* __restrict__ W3l, float* __restrict__ xsum) {
  const int blk = blockIdx.x, t = threadIdx.x;
  if (blk == 576) {  // zero xsum (16*256 f32)
#pragma unroll
    for (int i = 0; i < 16; ++i) xsum[t + i * 256] = 0.f;
    return;
  }
  if (blk < 64) {  // W1Th[e][c] = w1[c][e]
    __shared__ float tile[32][33];
    const int e0 = (blk & 7) * 32, c0 = (blk >> 3) * 32;
    const int tx = t & 31, ty = t >> 5;
#pragma unroll
    for (int i = 0; i < 4; ++i)
      tile[ty + i * 8][tx] = w1[(c0 + ty + i * 8) * 256 + e0 + tx];
    __syncthreads();
#pragma unroll
    for (int i = 0; i < 4; ++i)
      W1Th[(e0 + ty + i * 8) * 256 + c0 + tx] = f2b(tile[tx][ty + i * 8]);
  } else {
    const int i = (blk - 64) * 256 + t;  // 0..131071
    const int e = i & 0xffff;
    const float f = (i >> 16) ? w3[e] : w2[e];
    u16 h = f2b(f);
    if (i >> 16) { W3h[e] = h; W3l[e] = f2b(f - b2f(h)); }
    else         { W2h[e] = h; W2l[e] = f2b(f - b2f(h)); }
  }
}

// ---- stage 8 f32 -> hi/lo bf16 LDS (one uint4 each) + running sum --------
__device__ __forceinline__ void stage8(const float4 a, const float4 b,
                                       u16* dH, u16* dL, float& xa) {
  const float f[8] = {a.x, a.y, a.z, a.w, b.x, b.y, b.z, b.w};
  union { unsigned int w[4]; uint4 q; } uh, ul;
#pragma unroll
  for (int i = 0; i < 4; ++i) {
    const unsigned int h = cvt_pk_bf16(f[2 * i], f[2 * i + 1]);
    uh.w[i] = h;
    union { unsigned int u; float ff; } h0, h1;
    h0.u = h << 16;            // bf16 of f[2i] back to f32
    h1.u = h & 0xffff0000u;    // bf16 of f[2i+1] back to f32
    ul.w[i] = cvt_pk_bf16(f[2 * i] - h0.ff, f[2 * i + 1] - h1.ff);
    xa += f[2 * i] + f[2 * i + 1];
  }
  *(uint4*)dH = uh.q;
  *(uint4*)dL = ul.q;
}

// ---------------- Gram: half-M blocks, hoisted fragments -------------------
// grid = 16b x 16s x 2mh. 512 thr / 8 waves, wave tile 64x64, k-chunk 256.
// LDS: row r = 64B = 4x16B slots; slot q ^ ((r>>1)&3); both phases bank-free
// (measured 0 conflicts). 64 KiB total -> 2 blocks/CU.
__global__ __launch_bounds__(512, 4) void gram_kernel(
    const float* __restrict__ x, float* __restrict__ Gp, float* __restrict__ xsum) {
  __shared__ u16 lH[2][256 * 32], lL[2][256 * 32];  // 64 KB total
  const int b = blockIdx.x >> 5, s = (blockIdx.x >> 1) & 15, mh = blockIdx.x & 1;
  const float* Xb = x + (long)b * 1048576 + s * 256;
  const int t = threadIdx.x;
  const int lane = t & 63, wave = t >> 6;
  const int quad = lane >> 4, l16 = lane & 15;
  const int wml = (wave & 1) * 64 + mh * 128;  // A rows in slab
  const int wn = (wave >> 1) * 64;             // B rows
  const int r0 = t >> 2, qc = (t & 3) * 8;
  const int r1 = r0 + 128;                     // (r1>>1)&3 == (r0>>1)&3
  const int wq = (((t & 3) ^ ((r0 >> 1) & 3))) * 8;  // swizzled write slot
  const int rq = ((quad ^ ((l16 >> 1) & 3))) * 8;    // swizzled read slot
  floatx4 acc[4][4] = {};
  float xa0 = 0.f, xa1 = 0.f;  // per-row running sums (rows r0, r1)
  float4 p[4];
  p[0] = *(const float4*)(Xb + (long)r0 * 4096 + qc);
  p[1] = *(const float4*)(Xb + (long)r0 * 4096 + qc + 4);
  p[2] = *(const float4*)(Xb + (long)r1 * 4096 + qc);
  p[3] = *(const float4*)(Xb + (long)r1 * 4096 + qc + 4);
  stage8(p[0], p[1], lH[0] + r0 * 32 + wq, lL[0] + r0 * 32 + wq, xa0);
  stage8(p[2], p[3], lH[0] + r1 * 32 + wq, lL[0] + r1 * 32 + wq, xa1);
  __syncthreads();
  for (int kb = 0; kb < 8; ++kb) {
    const int cur = kb & 1, nxt = cur ^ 1;
    if (kb < 7) {  // issue next tile's loads; waitcnt lands after MFMA block
      const long kk = (kb + 1) * 32;
      p[0] = *(const float4*)(Xb + (long)r0 * 4096 + kk + qc);
      p[1] = *(const float4*)(Xb + (long)r0 * 4096 + kk + qc + 4);
      p[2] = *(const float4*)(Xb + (long)r1 * 4096 + kk + qc);
      p[3] = *(const float4*)(Xb + (long)r1 * 4096 + kk + qc + 4);
    }
    const u16* cH = lH[cur];
    const u16* cL = lL[cur];
    short8 ah[4], al[4];
#pragma unroll
    for (int i = 0; i < 4; ++i) {
      ah[i] = *(const short8*)(cH + (wml + i * 16 + l16) * 32 + rq);
      al[i] = *(const short8*)(cL + (wml + i * 16 + l16) * 32 + rq);
    }
#pragma unroll
    for (int j = 0; j < 4; ++j) {
      const short8 bh = *(const short8*)(cH + (wn + j * 16 + l16) * 32 + rq);
      const short8 bl = *(const short8*)(cL + (wn + j * 16 + l16) * 32 + rq);
#pragma unroll
      for (int i = 0; i < 4; ++i) {
        acc[i][j] = __builtin_amdgcn_mfma_f32_16x16x32_bf16(ah[i], bh, acc[i][j], 0, 0, 0);
        acc[i][j] = __builtin_amdgcn_mfma_f32_16x16x32_bf16(ah[i], bl, acc[i][j], 0, 0, 0);
        acc[i][j] = __builtin_amdgcn_mfma_f32_16x16x32_bf16(al[i], bh, acc[i][j], 0, 0, 0);
      }
    }
    if (kb < 7) {
      stage8(p[0], p[1], lH[nxt] + r0 * 32 + wq, lL[nxt] + r0 * 32 + wq, xa0);
      stage8(p[2], p[3], lH[nxt] + r1 * 32 + wq, lL[nxt] + r1 * 32 + wq, xa1);
    }
    __syncthreads();
  }
  if (mh == 0) {
    float v = xa0;
    v += __shfl_xor(v, 1);
    v += __shfl_xor(v, 2);
    if ((t & 3) == 0) atomicAdd(&xsum[b * 256 + r0], v);
    v = xa1;
    v += __shfl_xor(v, 1);
    v += __shfl_xor(v, 2);
    if ((t & 3) == 0) atomicAdd(&xsum[b * 256 + r1], v);
  }
  float* G = Gp + ((long)b * 16 + s) * 65536;
#pragma unroll
  for (int i = 0; i < 4; ++i) {
    const int row0 = wml + i * 16 + quad * 4;
#pragma unroll
    for (int j = 0; j < 4; ++j) {
      const int col = wn + j * 16 + l16;
#pragma unroll
      for (int r = 0; r < 4; ++r)
        G[(long)(row0 + r) * 256 + col] = acc[i][j][r];
    }
  }
}

// ------ Gram split-K reduction + hi/lo split (16 splits, float4 stream) ----
__global__ __launch_bounds__(256) void reduce_g_kernel(
    const float* __restrict__ Gp, u16* __restrict__ Gh, u16* __restrict__ Gl) {
  const long e = ((long)blockIdx.x * 256 + threadIdx.x) * 4;  // elem base
  const long base = ((e >> 16) << 20) + (e & 65535);          // b*16*65536 + idx
  float4 s = {0.f, 0.f, 0.f, 0.f};
#pragma unroll
  for (int i = 0; i < 16; ++i) {
    const float4 v = *(const float4*)(Gp + base + (long)i * 65536);
    s.x += v.x; s.y += v.y; s.z += v.z; s.w += v.w;
  }
  union { u16 h[4]; uint2 q; } oh, ol;
  const float sv[4] = {s.x, s.y, s.z, s.w};
#pragma unroll
  for (int c = 0; c < 4; ++c) {
    const u16 h = f2b(sv[c]);
    oh.h[c] = h;
    ol.h[c] = f2b(sv[c] - b2f(h));
  }
  *(uint2*)(Gh + e) = oh.q;
  *(uint2*)(Gl + e) = ol.q;
}

// ------- small 256x256x256 TN GEMM: 64x64 tiles, 256-block grid ------------
// EPI: 0 = f32 store, 1 = bf16 hi/lo store, 2 = bf16 hi store
template <bool X3, int EPI>
__global__ __launch_bounds__(256) void gemm_small(
    const u16* __restrict__ Ah, const u16* __restrict__ Al,
    const u16* __restrict__ Bh, const u16* __restrict__ Bl,
    long aBatch, long bBatch, long oBatch,
    float* __restrict__ outF, u16* __restrict__ outH, u16* __restrict__ outL) {
  constexpr int LR = 40;
  __shared__ u16 smem[(X3 ? 4 : 2) * 64 * LR];
  u16* lAh = smem;
  u16* lBh = smem + 64 * LR;
  u16* lAl = X3 ? (smem + 2 * 64 * LR) : nullptr;
  u16* lBl = X3 ? (smem + 3 * 64 * LR) : nullptr;
  const int b = blockIdx.z;
  const int tm = blockIdx.x & 3, tn = blockIdx.x >> 2;  // 4x4 tiles of 64
  const u16* Ahb = Ah + (long)b * aBatch + (long)tm * 64 * 256;
  const u16* Bhb = Bh + (long)b * bBatch + (long)tn * 64 * 256;
  const u16* Alb = X3 ? (Al + (long)b * aBatch + (long)tm * 64 * 256) : nullptr;
  const u16* Blb = X3 ? (Bl + (long)b * bBatch + (long)tn * 64 * 256) : nullptr;
  const int t = threadIdx.x;
  const int lane = t & 63, wave = t >> 6;
  const int quad = lane >> 4, l16 = lane & 15;
  const int wm = (wave & 1) * 32, wn = (wave >> 1) * 32;
  const int r = t >> 2, qc = (t & 3) * 8;
  floatx4 acc[2][2] = {};
  uint4 pA, pB, pAl = {}, pBl = {};
  pA = *(const uint4*)(Ahb + (long)r * 256 + qc);
  pB = *(const uint4*)(Bhb + (long)r * 256 + qc);
  if (X3) {
    pAl = *(const uint4*)(Alb + (long)r * 256 + qc);
    pBl = *(const uint4*)(Blb + (long)r * 256 + qc);
  }
  for (int kk = 0; kk < 256; kk += 32) {
    __syncthreads();
    *(uint4*)(lAh + r * LR + qc) = pA;
    *(uint4*)(lBh + r * LR + qc) = pB;
    if (X3) {
      *(uint4*)(lAl + r * LR + qc) = pAl;
      *(uint4*)(lBl + r * LR + qc) = pBl;
    }
    __syncthreads();
    if (kk < 224) {  // prefetch next k-step; overlaps MFMA below
      pA = *(const uint4*)(Ahb + (long)r * 256 + kk + 32 + qc);
      pB = *(const uint4*)(Bhb + (long)r * 256 + kk + 32 + qc);
      if (X3) {
        pAl = *(const uint4*)(Alb + (long)r * 256 + kk + 32 + qc);
        pBl = *(const uint4*)(Blb + (long)r * 256 + kk + 32 + qc);
      }
    }
    short8 afh[2], bfh[2], afl[2], bfl[2];
#pragma unroll
    for (int i = 0; i < 2; ++i) {
      afh[i] = *(const short8*)(lAh + (wm + i * 16 + l16) * LR + quad * 8);
      bfh[i] = *(const short8*)(lBh + (wn + i * 16 + l16) * LR + quad * 8);
      if (X3) {
        afl[i] = *(const short8*)(lAl + (wm + i * 16 + l16) * LR + quad * 8);
        bfl[i] = *(const short8*)(lBl + (wn + i * 16 + l16) * LR + quad * 8);
      }
    }
#pragma unroll
    for (int i = 0; i < 2; ++i)
#pragma unroll
      for (int j = 0; j < 2; ++j) {
        acc[i][j] = __builtin_amdgcn_mfma_f32_16x16x32_bf16(afh[i], bfh[j], acc[i][j], 0, 0, 0);
        if (X3) {
          acc[i][j] = __builtin_amdgcn_mfma_f32_16x16x32_bf16(afh[i], bfl[j], acc[i][j], 0, 0, 0);
          acc[i][j] = __builtin_amdgcn_mfma_f32_16x16x32_bf16(afl[i], bfh[j], acc[i][j], 0, 0, 0);
        }
      }
  }
  const long obase = (long)b * oBatch;
#pragma unroll
  for (int i = 0; i < 2; ++i) {
    const int mb = tm * 64 + wm + i * 16 + quad * 4;
#pragma unroll
    for (int j = 0; j < 2; ++j) {
      const int n = tn * 64 + wn + j * 16 + l16;
#pragma unroll
      for (int rr = 0; rr < 4; ++rr) {
        const float v = acc[i][j][rr];
        const long idx = obase + (long)(mb + rr) * 256 + n;
        if (EPI == 0) {
          outF[idx] = v;
        } else if (EPI == 1) {
          u16 h = f2b(v);
          outH[idx] = h;
          outL[idx] = f2b(v - b2f(h));
        } else {
          outH[idx] = f2b(v);
        }
      }
    }
  }
}

// ------------- out = Mh * X^T + bb : 256x128 per block, 8 waves ------------
// A (Mh bf16): global_load_lds width-16, double-buffered, rows 64B (LR=32),
// XOR slot q^((r>>1)&3) applied to per-lane GLOBAL source col + read slot
// (LDS itself linear -- rule 21). B (x f32): 8 coalesced scalar dwords,
// cvt_pk pair-pack into lB (LR=40); lane t writes nl=(t&31)+32i so 8
// consecutive lanes hit distinct banks (write phase now conflict-free).
__global__ __launch_bounds__(512, 2) void gemm_out(
    const u16* __restrict__ Mh, const float* __restrict__ x,
    const float* __restrict__ bb, float* __restrict__ out) {
  __shared__ u16 lA[2][256 * 32];  // 2 x 16 KB
  __shared__ u16 lB[128 * 40];     // 10 KB
  const int b = blockIdx.z;
  const int tn = blockIdx.x;  // 0..31
  const u16* Ab = Mh + (long)b * 65536;
  const float* Xb = x + (long)b * 1048576 + tn * 128;
  const int t = threadIdx.x;
  const int lane = t & 63, wave = t >> 6;
  const int quad = lane >> 4, l16 = lane & 15;
  const int wm = (wave & 3) * 64;     // 4 m-waves
  const int wn = (wave >> 2) * 64;    // 2 n-waves
  const int erp = (t >> 5) * 2;       // e-row pair base 0..30
  const int n0 = t & 31;              // B col base (cols n0+32i)
  const int ra = t >> 2;              // A row (lane>>2 within wave chunk)
  const int sc = ((t & 3) ^ ((t >> 3) & 3)) * 8;   // pre-swizzled A src col
  const int rqA = (quad ^ ((l16 >> 1) & 3)) * 8;   // A read slot
  u16* wA0 = &lA[0][0] + wave * 16 * 32;           // wave-uniform LDS bases
  u16* wA1 = &lA[1][0] + wave * 16 * 32;
  floatx4 acc[4][4] = {};
  float pb[8];
  // prologue: A k-step 0 -> buf0; B regs for k-step 0
  gload_lds16(Ab + (long)ra * 256 + sc, wA0);
  gload_lds16(Ab + (long)(ra + 128) * 256 + sc, wA0 + 128 * 32);
#pragma unroll
  for (int i = 0; i < 4; ++i) {
    pb[i]     = Xb[(long)erp * 4096 + n0 + 32 * i];
    pb[4 + i] = Xb[(long)(erp + 1) * 4096 + n0 + 32 * i];
  }
  for (int s = 0; s < 8; ++s) {
    const int kk = s * 32;
    const u16* curA = lA[s & 1];
    __syncthreads();  // drains gloads into buf[s&1] + pb loads (vmcnt 0)
    // stage lB: pair-pack (erp, erp+1) rows, XOR e-block swizzle
#pragma unroll
    for (int i = 0; i < 4; ++i) {
      const int nl = n0 + 32 * i;
      const int sb = (erp >> 3) ^ ((nl >> 4) & 3);
      *(unsigned int*)(lB + nl * 40 + sb * 8 + (erp & 7)) =
          cvt_pk_bf16(pb[i], pb[4 + i]);
    }
    __syncthreads();  // lB visible
    if (s < 7) {      // next-step prefetch overlaps MFMA phase
      const int k2 = kk + 32;
      u16* nA = (s & 1) ? wA0 : wA1;
      gload_lds16(Ab + (long)ra * 256 + k2 + sc, nA);
      gload_lds16(Ab + (long)(ra + 128) * 256 + k2 + sc, nA + 128 * 32);
#pragma unroll
      for (int i = 0; i < 4; ++i) {
        pb[i]     = Xb[(long)(k2 + erp) * 4096 + n0 + 32 * i];
        pb[4 + i] = Xb[(long)(k2 + erp + 1) * 4096 + n0 + 32 * i];
      }
    }
    short8 af[4];
#pragma unroll
    for (int i = 0; i < 4; ++i)
      af[i] = *(const short8*)(curA + (wm + i * 16 + l16) * 32 + rqA);
#pragma unroll
    for (int j = 0; j < 4; ++j) {
      const int n = wn + j * 16 + l16;
      const int rb = quad ^ ((n >> 4) & 3);
      const short8 bf = *(const short8*)(lB + n * 40 + rb * 8);
#pragma unroll
      for (int i = 0; i < 4; ++i)
        acc[i][j] = __builtin_amdgcn_mfma_f32_16x16x32_bf16(af[i], bf, acc[i][j], 0, 0, 0);
    }
  }
  const long obase = (long)b * 1048576;
#pragma unroll
  for (int i = 0; i < 4; ++i) {
    const int mb = wm + i * 16 + quad * 4;
#pragma unroll
    for (int j = 0; j < 4; ++j) {
      const int n = tn * 128 + wn + j * 16 + l16;
#pragma unroll
      for (int r = 0; r < 4; ++r)
        out[obase + (long)(mb + r) * 4096 + n] = acc[i][j][r] + bb[b * 256 + mb + r];
    }
  }
}

// ---------------- bias prep: s2[b][a]=w2[a,:]·xsum[b], s3 likewise --------
__global__ __launch_bounds__(512) void bias_prep_kernel(
    const float* __restrict__ w2, const float* __restrict__ w3,
    const float* __restrict__ xsum, float* __restrict__ S2, float* __restrict__ S3) {
  __shared__ float xs[256];
  const int b = blockIdx.x, t = threadIdx.x;
  if (t < 256) xs[t] = xsum[b * 256 + t];
  __syncthreads();
  const float* wm = (t < 256) ? w2 : w3;
  const int a = t & 255;
  float s = 0.f;
#pragma unroll 4
  for (int c = 0; c < 256; ++c) s += wm[a * 256 + c] * xs[c];
  if (t < 256) S2[b * 256 + a] = s;
  else         S3[b * 256 + a] = s;
}

// ---------------- softmax pass1: per-block (max, sumexp) ------------------
__global__ __launch_bounds__(256) void softmax_pass1(
    const float* __restrict__ Lt, const float* __restrict__ S2, const float* __restrict__ S3,
    const float* __restrict__ b2, const float* __restrict__ b3,
    float* __restrict__ bm, float* __restrict__ bs) {
  __shared__ float ls2[256], lb2[256];
  __shared__ float redm[4], reds[4];
  const int b = blockIdx.y, blk = blockIdx.x, t = threadIdx.x;
  ls2[t] = S2[b * 256 + t];
  lb2[t] = b2[t];
  __syncthreads();
  const int fw0 = blk * 2048 + t * 8;
  const int d = fw0 >> 8, a0 = fw0 & 255;
  const float c1 = b3[d];
  const float c0 = S3[b * 256 + d] + 4096.f * c1;
  const long base = (long)b * 65536 + fw0;
  float4 v0 = *(const float4*)(Lt + base);
  float4 v1 = *(const float4*)(Lt + base + 4);
  float v[8] = {v0.x, v0.y, v0.z, v0.w, v1.x, v1.y, v1.z, v1.w};
  float m = -3.4e38f;
#pragma unroll
  for (int i = 0; i < 8; ++i) {
    v[i] += lb2[a0 + i] * c0 + c1 * ls2[a0 + i];
    m = fmaxf(m, v[i]);
  }
  for (int o = 32; o; o >>= 1) m = fmaxf(m, __shfl_xor(m, o));
  const int wid = t >> 6, lane = t & 63;
  if (lane == 0) redm[wid] = m;
  __syncthreads();
  const float bmax = fmaxf(fmaxf(redm[0], redm[1]), fmaxf(redm[2], redm[3]));
  float s = 0.f;
#pragma unroll
  for (int i = 0; i < 8; ++i) s += __expf(v[i] - bmax);
  for (int o = 32; o; o >>= 1) s += __shfl_xor(s, o);
  if (lane == 0) reds[wid] = s;
  __syncthreads();
  if (t == 0) {
    bm[b * 32 + blk] = bmax;
    bs[b * 32 + blk] = reds[0] + reds[1] + reds[2] + reds[3];
  }
}

// -- softmax pass3: inline combine + write WT bf16 + fused bb[d]=WT·b1 ------
__global__ __launch_bounds__(256) void softmax_pass3(
    const float* __restrict__ Lt, const float* __restrict__ S2, const float* __restrict__ S3,
    const float* __restrict__ b2, const float* __restrict__ b3,
    const float* __restrict__ bm, const float* __restrict__ bs,
    const float* __restrict__ b1, u16* __restrict__ WTh, float* __restrict__ bb) {
  __shared__ float ls2[256], lb2[256], lb1[256];
  __shared__ float sM, sInv;
  const int b = blockIdx.y, blk = blockIdx.x, t = threadIdx.x;
  if (t < 64) {  // combine 32 block pairs (wave 0 only)
    const float m = (t < 32) ? bm[b * 32 + t] : -3.4e38f;
    float s = (t < 32) ? bs[b * 32 + t] : 0.f;
    float M = m;
    for (int o = 32; o; o >>= 1) M = fmaxf(M, __shfl_xor(M, o));
    s *= __expf(m - M);
    for (int o = 32; o; o >>= 1) s += __shfl_xor(s, o);
    if (t == 0) { sM = M; sInv = 1.0f / s; }
  }
  ls2[t] = S2[b * 256 + t];
  lb2[t] = b2[t];
  lb1[t] = b1[t];
  __syncthreads();
  const float M = sM, inv = sInv;
  const int fw0 = blk * 2048 + t * 8;
  const int d = fw0 >> 8, a0 = fw0 & 255;
  const float c1 = b3[d];
  const float c0 = S3[b * 256 + d] + 4096.f * c1;
  const long base = (long)b * 65536 + fw0;
  float4 v0 = *(const float4*)(Lt + base);
  float4 v1 = *(const float4*)(Lt + base + 4);
  float v[8] = {v0.x, v0.y, v0.z, v0.w, v1.x, v1.y, v1.z, v1.w};
  union { u16 h[8]; uint4 q; } o;
  float bsum = 0.f;
#pragma unroll
  for (int i = 0; i < 8; ++i) {
    const float vv = v[i] + lb2[a0 + i] * c0 + c1 * ls2[a0 + i];
    const float w = __expf(vv - M) * inv;
    o.h[i] = f2b(w);
    bsum += w * lb1[a0 + i];
  }
  *(uint4*)(WTh + base) = o.q;
  // row d spans 32 consecutive threads
  for (int off = 16; off; off >>= 1) bsum += __shfl_xor(bsum, off);
  if ((t & 31) == 0) bb[b * 256 + d] = bsum;
}

extern "C" void kernel_launch(void* const* d_in, const int* in_sizes, int n_in,
                              void* d_out, int out_size, void* d_ws, size_t ws_size,
                              hipStream_t stream) {
  const float* x  = (const float*)d_in[0];
  const float* w1 = (const float*)d_in[1];
  const float* b1 = (const float*)d_in[2];
  const float* w2 = (const float*)d_in[3];
  const float* b2 = (const float*)d_in[4];
  const float* w3 = (const float*)d_in[5];
  const float* b3 = (const float*)d_in[6];
  float* out = (float*)d_out;

  char* ws = (char*)d_ws;
  size_t off = 0;
  auto alloc = [&](size_t bytes) {
    void* p = ws + off;
    off += (bytes + 255) & ~(size_t)255;
    return p;
  };
  float* Gp = (float*)alloc(16ull * 16 * 65536 * 4);   // 64 MiB split-K partials
  float* xsum = (float*)alloc(16 * 256 * 4);
  u16* Gh   = (u16*)alloc(16ull * 65536 * 2);
  u16* Gl   = (u16*)alloc(16ull * 65536 * 2);
  u16* T3h  = (u16*)alloc(16ull * 65536 * 2);
  u16* T3l  = (u16*)alloc(16ull * 65536 * 2);
  float* Lb = (float*)alloc(16ull * 65536 * 4);        // Lt[d][a]
  u16* WTh  = (u16*)alloc(16ull * 65536 * 2);
  u16* Mh   = (u16*)alloc(16ull * 65536 * 2);
  u16* W1Th = (u16*)alloc(65536 * 2);
  u16* W2h  = (u16*)alloc(65536 * 2);
  u16* W2l  = (u16*)alloc(65536 * 2);
  u16* W3h  = (u16*)alloc(65536 * 2);
  u16* W3l  = (u16*)alloc(65536 * 2);
  float* S2   = (float*)alloc(16 * 256 * 4);
  float* S3   = (float*)alloc(16 * 256 * 4);
  float* bmx  = (float*)alloc(16 * 32 * 4);
  float* bsx  = (float*)alloc(16 * 32 * 4);
  float* bb   = (float*)alloc(16 * 256 * 4);

  prep_w_kernel<<<577, 256, 0, stream>>>(w1, w2, w3, W1Th, W2h, W2l, W3h, W3l, xsum);

  // Gram partials: 16 batches x 16 splits x 2 m-halves (xsum fused, mh==0).
  gram_kernel<<<512, 512, 0, stream>>>(x, Gp, xsum);
  reduce_g_kernel<<<1024, 256, 0, stream>>>(Gp, Gh, Gl);

  // T3 = W3 * G (G symmetric -> TN ok). 64x64 tiles, 256 blocks.
  gemm_small<true, 1><<<dim3(16, 1, 16), 256, 0, stream>>>(
      W3h, W3l, Gh, Gl, 0, 65536, 65536, nullptr, T3h, T3l);
  // Lt = T3 * W2^T  ->  Lt[d][a] = logits[a][d].
  gemm_small<true, 0><<<dim3(16, 1, 16), 256, 0, stream>>>(
      T3h, T3l, W2h, W2l, 65536, 0, 65536, Lb, nullptr, nullptr);

  // softmax: bias prep + pass1 + fused combine/write/bb pass3
  bias_prep_kernel<<<16, 512, 0, stream>>>(w2, w3, xsum, S2, S3);
  softmax_pass1<<<dim3(32, 16), 256, 0, stream>>>(Lb, S2, S3, b2, b3, bmx, bsx);
  softmax_pass3<<<dim3(32, 16), 256, 0, stream>>>(Lb, S2, S3, b2, b3, bmx, bsx,
                                                  b1, WTh, bb);

  // out-chain: Mh = WT*W1T (bf16), out = Mh*X^T + bb
  gemm_small<false, 2><<<dim3(16, 1, 16), 256, 0, stream>>>(
      WTh, nullptr, W1Th, nullptr, 65536, 0, 65536, nullptr, Mh, nullptr);
  gemm_out<<<dim3(32, 1, 16), 512, 0, stream>>>(Mh, x, bb, out);
}

// Round 6
// 217.137 us; speedup vs baseline: 1.2287x; 1.0060x over previous
//
#include <hip/hip_runtime.h>

// GlobalChannelAttention: B=16, C=256, H*W=4096
//
// Pipeline (TN-form GEMMs: C[M,N] = sum_k A[m][k]*B[n][k], K contiguous):
//   1. prep_w: w1 -> W1Th (bf16 transposed), w2/w3 -> hi/lo bf16, zero xsum
//   2. gram: G[b] = X X^T from raw x f32 (hi/lo in SEPARATE LDS slabs, 3
//      MFMAs hh+hl+lh). HALF-M blocks: grid 16b x 16splits x 2mhalf.
//   3. reduce_g: sum 16 partials -> Gh/Gl bf16 (float4-vectorized stream).
//      T3 = W3*G (G symmetric), Lt = T3*W2^T == logits TRANSPOSED (Lt[d][a]).
//   4. global softmax: pass1 block partials; pass3 combine + write WT bf16
//      + fused bb[d] = sum_c WT[d][c]*b1[c].
//   5. Mh = WT*W1T (bf16); out = Mh*X^T + bb, 256x128 tiles, 512 thr.
//
// Precision: logit chain bf16 hi/lo x3 (err ~2^-17 rel); out chain plain bf16.
// R7: atomic-f32 Gram epilogue regressed (16-way same-address L2 contention).
// R8: k-interleaved hi/lo loses hi*lo cross terms -> accuracy fail.
// R9: 128-VGPR acc forced fragment rematerialization -> LDS-read bound.
// R10: separate xsum_kernel re-read 64MB of x -- folded back into gram.
// R11: gram latency-bound -> 16 k-splits, 64KiB LDS XOR-swizzle, cvt_pk
//     staging, reg-prefetch. gram 46->41us, 0 bank conflicts (verified R5).
// R12/R13: launch_bounds(512,4) = 4 BLOCKS/CU (CUDA semantics) -> 64-VGPR
//     cap -> scratch spill. REGRESSED 45->73us.
// R14: (512,2) + per-j bf: spill gone, 41.7us; 2.36M lB-write conflicts.
// R15: gemm_out gload_lds dbuf A + conflict-free lB write remap; gemm_out
//     left top-5 (<40.5us). Total 218. Top-5 now: harness fill (41us,
//     uncontrollable) + gram 40.6 + everything else <40.5.
// R16 (this round): the 3 gemm_smalls are 1 block/CU, 1 wave/SIMD with 16
//     barriers each -- fully exposed latency. Full-panel LDS staging
//     ([64][264] pad, 528B stride: uniform 8 lanes/16B bank-group on both
//     write & read = conflict-free; X3 132KB / non-X3 66KB fits 160KB at
//     the 1 block/CU we already have), ONE barrier, then 8 barrier-free
//     k-steps of pure ds_read+MFMA.

typedef unsigned short u16;
typedef __attribute__((ext_vector_type(8))) short short8;
typedef __attribute__((ext_vector_type(4))) float floatx4;

__device__ __forceinline__ u16 f2b(float f) {
  union { float f; unsigned int u; } v; v.f = f;
  unsigned int u = v.u;
  return (u16)((u + 0x7fffu + ((u >> 16) & 1u)) >> 16);  // RNE
}
__device__ __forceinline__ float b2f(u16 h) {
  union { unsigned int u; float f; } v; v.u = ((unsigned int)h) << 16;
  return v.f;
}
// HW packed f32->bf16 (RNE), lo -> bits[15:0], hi -> bits[31:16].
__device__ __forceinline__ unsigned int cvt_pk_bf16(float lo, float hi) {
  unsigned int r;
  asm("v_cvt_pk_bf16_f32 %0, %1, %2" : "=v"(r) : "v"(lo), "v"(hi));
  return r;
}
// async global->LDS, 16B per lane. LDS dest = wave-uniform base + lane*16.
__device__ __forceinline__ void gload_lds16(const u16* g, u16* l) {
  __builtin_amdgcn_global_load_lds(
      (const __attribute__((address_space(1))) unsigned int*)(const void*)g,
      (__attribute__((address_space(3))) unsigned int*)(void*)l, 16, 0, 0);
}

// ------- merged W prep: transpose w1 + split w2/w3 + zero xsum -------------
__global__ __launch_bounds__(256) void prep_w_kernel(
    const float* __restrict__ w1, const float* __restrict__ w2, const float* __restrict__ w3,
    u16* __restrict__ W1Th, u16* __restrict__ W2h, u16* __restrict__ W2l,
    u16* __restrict__ W3h, u16* __restrict__ W3l, float* __restrict__ xsum) {
  const int blk = blockIdx.x, t = threadIdx.x;
  if (blk == 576) {  // zero xsum (16*256 f32)
#pragma unroll
    for (int i = 0; i < 16; ++i) xsum[t + i * 256] = 0.f;
    return;
  }
  if (blk < 64) {  // W1Th[e][c] = w1[c][e]
    __shared__ float tile[32][33];
    const int e0 = (blk & 7) * 32, c0 = (blk >> 3) * 32;
    const int tx = t & 31, ty = t >> 5;
#pragma unroll
    for (int i = 0; i < 4; ++i)
      tile[ty + i * 8][tx] = w1[(c0 + ty + i * 8) * 256 + e0 + tx];
    __syncthreads();
#pragma unroll
    for (int i = 0; i < 4; ++i)
      W1Th[(e0 + ty + i * 8) * 256 + c0 + tx] = f2b(tile[tx][ty + i * 8]);
  } else {
    const int i = (blk - 64) * 256 + t;  // 0..131071
    const int e = i & 0xffff;
    const float f = (i >> 16) ? w3[e] : w2[e];
    u16 h = f2b(f);
    if (i >> 16) { W3h[e] = h; W3l[e] = f2b(f - b2f(h)); }
    else         { W2h[e] = h; W2l[e] = f2b(f - b2f(h)); }
  }
}

// ---- stage 8 f32 -> hi/lo bf16 LDS (one uint4 each) + running sum --------
__device__ __forceinline__ void stage8(const float4 a, const float4 b,
                                       u16* dH, u16* dL, float& xa) {
  const float f[8] = {a.x, a.y, a.z, a.w, b.x, b.y, b.z, b.w};
  union { unsigned int w[4]; uint4 q; } uh, ul;
#pragma unroll
  for (int i = 0; i < 4; ++i) {
    const unsigned int h = cvt_pk_bf16(f[2 * i], f[2 * i + 1]);
    uh.w[i] = h;
    union { unsigned int u; float ff; } h0, h1;
    h0.u = h << 16;            // bf16 of f[2i] back to f32
    h1.u = h & 0xffff0000u;    // bf16 of f[2i+1] back to f32
    ul.w[i] = cvt_pk_bf16(f[2 * i] - h0.ff, f[2 * i + 1] - h1.ff);
    xa += f[2 * i] + f[2 * i + 1];
  }
  *(uint4*)dH = uh.q;
  *(uint4*)dL = ul.q;
}

// ---------------- Gram: half-M blocks, hoisted fragments -------------------
// grid = 16b x 16s x 2mh. 512 thr / 8 waves, wave tile 64x64, k-chunk 256.
// LDS: row r = 64B = 4x16B slots; slot q ^ ((r>>1)&3); both phases bank-free
// (measured 0 conflicts). 64 KiB total -> 2 blocks/CU.
__global__ __launch_bounds__(512, 4) void gram_kernel(
    const float* __restrict__ x, float* __restrict__ Gp, float* __restrict__ xsum) {
  __shared__ u16 lH[2][256 * 32], lL[2][256 * 32];  // 64 KB total
  const int b = blockIdx.x >> 5, s = (blockIdx.x >> 1) & 15, mh = blockIdx.x & 1;
  const float* Xb = x + (long)b * 1048576 + s * 256;
  const int t = threadIdx.x;
  const int lane = t & 63, wave = t >> 6;
  const int quad = lane >> 4, l16 = lane & 15;
  const int wml = (wave & 1) * 64 + mh * 128;  // A rows in slab
  const int wn = (wave >> 1) * 64;             // B rows
  const int r0 = t >> 2, qc = (t & 3) * 8;
  const int r1 = r0 + 128;                     // (r1>>1)&3 == (r0>>1)&3
  const int wq = (((t & 3) ^ ((r0 >> 1) & 3))) * 8;  // swizzled write slot
  const int rq = ((quad ^ ((l16 >> 1) & 3))) * 8;    // swizzled read slot
  floatx4 acc[4][4] = {};
  float xa0 = 0.f, xa1 = 0.f;  // per-row running sums (rows r0, r1)
  float4 p[4];
  p[0] = *(const float4*)(Xb + (long)r0 * 4096 + qc);
  p[1] = *(const float4*)(Xb + (long)r0 * 4096 + qc + 4);
  p[2] = *(const float4*)(Xb + (long)r1 * 4096 + qc);
  p[3] = *(const float4*)(Xb + (long)r1 * 4096 + qc + 4);
  stage8(p[0], p[1], lH[0] + r0 * 32 + wq, lL[0] + r0 * 32 + wq, xa0);
  stage8(p[2], p[3], lH[0] + r1 * 32 + wq, lL[0] + r1 * 32 + wq, xa1);
  __syncthreads();
  for (int kb = 0; kb < 8; ++kb) {
    const int cur = kb & 1, nxt = cur ^ 1;
    if (kb < 7) {  // issue next tile's loads; waitcnt lands after MFMA block
      const long kk = (kb + 1) * 32;
      p[0] = *(const float4*)(Xb + (long)r0 * 4096 + kk + qc);
      p[1] = *(const float4*)(Xb + (long)r0 * 4096 + kk + qc + 4);
      p[2] = *(const float4*)(Xb + (long)r1 * 4096 + kk + qc);
      p[3] = *(const float4*)(Xb + (long)r1 * 4096 + kk + qc + 4);
    }
    const u16* cH = lH[cur];
    const u16* cL = lL[cur];
    short8 ah[4], al[4];
#pragma unroll
    for (int i = 0; i < 4; ++i) {
      ah[i] = *(const short8*)(cH + (wml + i * 16 + l16) * 32 + rq);
      al[i] = *(const short8*)(cL + (wml + i * 16 + l16) * 32 + rq);
    }
#pragma unroll
    for (int j = 0; j < 4; ++j) {
      const short8 bh = *(const short8*)(cH + (wn + j * 16 + l16) * 32 + rq);
      const short8 bl = *(const short8*)(cL + (wn + j * 16 + l16) * 32 + rq);
#pragma unroll
      for (int i = 0; i < 4; ++i) {
        acc[i][j] = __builtin_amdgcn_mfma_f32_16x16x32_bf16(ah[i], bh, acc[i][j], 0, 0, 0);
        acc[i][j] = __builtin_amdgcn_mfma_f32_16x16x32_bf16(ah[i], bl, acc[i][j], 0, 0, 0);
        acc[i][j] = __builtin_amdgcn_mfma_f32_16x16x32_bf16(al[i], bh, acc[i][j], 0, 0, 0);
      }
    }
    if (kb < 7) {
      stage8(p[0], p[1], lH[nxt] + r0 * 32 + wq, lL[nxt] + r0 * 32 + wq, xa0);
      stage8(p[2], p[3], lH[nxt] + r1 * 32 + wq, lL[nxt] + r1 * 32 + wq, xa1);
    }
    __syncthreads();
  }
  if (mh == 0) {
    float v = xa0;
    v += __shfl_xor(v, 1);
    v += __shfl_xor(v, 2);
    if ((t & 3) == 0) atomicAdd(&xsum[b * 256 + r0], v);
    v = xa1;
    v += __shfl_xor(v, 1);
    v += __shfl_xor(v, 2);
    if ((t & 3) == 0) atomicAdd(&xsum[b * 256 + r1], v);
  }
  float* G = Gp + ((long)b * 16 + s) * 65536;
#pragma unroll
  for (int i = 0; i < 4; ++i) {
    const int row0 = wml + i * 16 + quad * 4;
#pragma unroll
    for (int j = 0; j < 4; ++j) {
      const int col = wn + j * 16 + l16;
#pragma unroll
      for (int r = 0; r < 4; ++r)
        G[(long)(row0 + r) * 256 + col] = acc[i][j][r];
    }
  }
}

// ------ Gram split-K reduction + hi/lo split (16 splits, float4 stream) ----
__global__ __launch_bounds__(256) void reduce_g_kernel(
    const float* __restrict__ Gp, u16* __restrict__ Gh, u16* __restrict__ Gl) {
  const long e = ((long)blockIdx.x * 256 + threadIdx.x) * 4;  // elem base
  const long base = ((e >> 16) << 20) + (e & 65535);          // b*16*65536 + idx
  float4 s = {0.f, 0.f, 0.f, 0.f};
#pragma unroll
  for (int i = 0; i < 16; ++i) {
    const float4 v = *(const float4*)(Gp + base + (long)i * 65536);
    s.x += v.x; s.y += v.y; s.z += v.z; s.w += v.w;
  }
  union { u16 h[4]; uint2 q; } oh, ol;
  const float sv[4] = {s.x, s.y, s.z, s.w};
#pragma unroll
  for (int c = 0; c < 4; ++c) {
    const u16 h = f2b(sv[c]);
    oh.h[c] = h;
    ol.h[c] = f2b(sv[c] - b2f(h));
  }
  *(uint2*)(Gh + e) = oh.q;
  *(uint2*)(Gl + e) = ol.q;
}

// ------- small 256x256x256 TN GEMM: full-panel LDS, 64x64 tiles ------------
// Full A(64x256) + B(64x256) hi(/lo) panels staged ONCE into padded LDS
// ([64][264] u16, 528B row stride -> uniform 8 lanes per 16B bank-group on
// both staging writes and fragment reads = conflict-free), one barrier, then
// 8 barrier-free k-steps of pure ds_read+MFMA. Grid 256 = 1 block/CU;
// X3 LDS 132KB, non-X3 66KB (<=160KB). EPI: 0=f32, 1=bf16 hi/lo, 2=bf16 hi.
template <bool X3, int EPI>
__global__ __launch_bounds__(256) void gemm_small(
    const u16* __restrict__ Ah, const u16* __restrict__ Al,
    const u16* __restrict__ Bh, const u16* __restrict__ Bl,
    long aBatch, long bBatch, long oBatch,
    float* __restrict__ outF, u16* __restrict__ outH, u16* __restrict__ outL) {
  constexpr int LW = 264;  // row stride in elems (528 B)
  __shared__ u16 smem[(X3 ? 4 : 2) * 64 * LW];
  u16* lAh = smem;
  u16* lBh = smem + 64 * LW;
  u16* lAl = X3 ? (smem + 2 * 64 * LW) : nullptr;
  u16* lBl = X3 ? (smem + 3 * 64 * LW) : nullptr;
  const int b = blockIdx.z;
  const int tm = blockIdx.x & 3, tn = blockIdx.x >> 2;  // 4x4 tiles of 64
  const u16* Ahb = Ah + (long)b * aBatch + (long)tm * 64 * 256;
  const u16* Bhb = Bh + (long)b * bBatch + (long)tn * 64 * 256;
  const int t = threadIdx.x;
  const int lane = t & 63, wave = t >> 6;
  const int quad = lane >> 4, l16 = lane & 15;
  const int wm = (wave & 1) * 32, wn = (wave >> 1) * 32;
  const int r = t >> 2, c4 = t & 3;  // staging: row r, slots c4+4j (16B each)
  {
    uint4 tmp[8];
#pragma unroll
    for (int j = 0; j < 8; ++j)
      tmp[j] = *(const uint4*)(Ahb + (long)r * 256 + (c4 + 4 * j) * 8);
#pragma unroll
    for (int j = 0; j < 8; ++j)
      *(uint4*)(lAh + r * LW + (c4 + 4 * j) * 8) = tmp[j];
#pragma unroll
    for (int j = 0; j < 8; ++j)
      tmp[j] = *(const uint4*)(Bhb + (long)r * 256 + (c4 + 4 * j) * 8);
#pragma unroll
    for (int j = 0; j < 8; ++j)
      *(uint4*)(lBh + r * LW + (c4 + 4 * j) * 8) = tmp[j];
    if (X3) {
      const u16* Alb = Al + (long)b * aBatch + (long)tm * 64 * 256;
      const u16* Blb = Bl + (long)b * bBatch + (long)tn * 64 * 256;
#pragma unroll
      for (int j = 0; j < 8; ++j)
        tmp[j] = *(const uint4*)(Alb + (long)r * 256 + (c4 + 4 * j) * 8);
#pragma unroll
      for (int j = 0; j < 8; ++j)
        *(uint4*)(lAl + r * LW + (c4 + 4 * j) * 8) = tmp[j];
#pragma unroll
      for (int j = 0; j < 8; ++j)
        tmp[j] = *(const uint4*)(Blb + (long)r * 256 + (c4 + 4 * j) * 8);
#pragma unroll
      for (int j = 0; j < 8; ++j)
        *(uint4*)(lBl + r * LW + (c4 + 4 * j) * 8) = tmp[j];
    }
  }
  __syncthreads();  // the ONLY barrier
  floatx4 acc[2][2] = {};
#pragma unroll
  for (int kk = 0; kk < 8; ++kk) {
    const int co = kk * 32 + quad * 8;
    short8 afh[2], bfh[2];
#pragma unroll
    for (int i = 0; i < 2; ++i) {
      afh[i] = *(const short8*)(lAh + (wm + i * 16 + l16) * LW + co);
      bfh[i] = *(const short8*)(lBh + (wn + i * 16 + l16) * LW + co);
    }
    if (X3) {
      short8 afl[2], bfl[2];
#pragma unroll
      for (int i = 0; i < 2; ++i) {
        afl[i] = *(const short8*)(lAl + (wm + i * 16 + l16) * LW + co);
        bfl[i] = *(const short8*)(lBl + (wn + i * 16 + l16) * LW + co);
      }
#pragma unroll
      for (int i = 0; i < 2; ++i)
#pragma unroll
        for (int j = 0; j < 2; ++j) {
          acc[i][j] = __builtin_amdgcn_mfma_f32_16x16x32_bf16(afh[i], bfh[j], acc[i][j], 0, 0, 0);
          acc[i][j] = __builtin_amdgcn_mfma_f32_16x16x32_bf16(afh[i], bfl[j], acc[i][j], 0, 0, 0);
          acc[i][j] = __builtin_amdgcn_mfma_f32_16x16x32_bf16(afl[i], bfh[j], acc[i][j], 0, 0, 0);
        }
    } else {
#pragma unroll
      for (int i = 0; i < 2; ++i)
#pragma unroll
        for (int j = 0; j < 2; ++j)
          acc[i][j] = __builtin_amdgcn_mfma_f32_16x16x32_bf16(afh[i], bfh[j], acc[i][j], 0, 0, 0);
    }
  }
  const long obase = (long)b * oBatch;
#pragma unroll
  for (int i = 0; i < 2; ++i) {
    const int mb = tm * 64 + wm + i * 16 + quad * 4;
#pragma unroll
    for (int j = 0; j < 2; ++j) {
      const int n = tn * 64 + wn + j * 16 + l16;
#pragma unroll
      for (int rr = 0; rr < 4; ++rr) {
        const float v = acc[i][j][rr];
        const long idx = obase + (long)(mb + rr) * 256 + n;
        if (EPI == 0) {
          outF[idx] = v;
        } else if (EPI == 1) {
          u16 h = f2b(v);
          outH[idx] = h;
          outL[idx] = f2b(v - b2f(h));
        } else {
          outH[idx] = f2b(v);
        }
      }
    }
  }
}

// ------------- out = Mh * X^T + bb : 256x128 per block, 8 waves ------------
// A (Mh bf16): global_load_lds width-16, double-buffered, rows 64B (LR=32),
// XOR slot q^((r>>1)&3) applied to per-lane GLOBAL source col + read slot
// (LDS itself linear -- rule 21). B (x f32): 8 coalesced scalar dwords,
// cvt_pk pair-pack into lB (LR=40); lane t writes nl=(t&31)+32i so 8
// consecutive lanes hit distinct banks (write phase conflict-free).
__global__ __launch_bounds__(512, 2) void gemm_out(
    const u16* __restrict__ Mh, const float* __restrict__ x,
    const float* __restrict__ bb, float* __restrict__ out) {
  __shared__ u16 lA[2][256 * 32];  // 2 x 16 KB
  __shared__ u16 lB[128 * 40];     // 10 KB
  const int b = blockIdx.z;
  const int tn = blockIdx.x;  // 0..31
  const u16* Ab = Mh + (long)b * 65536;
  const float* Xb = x + (long)b * 1048576 + tn * 128;
  const int t = threadIdx.x;
  const int lane = t & 63, wave = t >> 6;
  const int quad = lane >> 4, l16 = lane & 15;
  const int wm = (wave & 3) * 64;     // 4 m-waves
  const int wn = (wave >> 2) * 64;    // 2 n-waves
  const int erp = (t >> 5) * 2;       // e-row pair base 0..30
  const int n0 = t & 31;              // B col base (cols n0+32i)
  const int ra = t >> 2;              // A row (lane>>2 within wave chunk)
  const int sc = ((t & 3) ^ ((t >> 3) & 3)) * 8;   // pre-swizzled A src col
  const int rqA = (quad ^ ((l16 >> 1) & 3)) * 8;   // A read slot
  u16* wA0 = &lA[0][0] + wave * 16 * 32;           // wave-uniform LDS bases
  u16* wA1 = &lA[1][0] + wave * 16 * 32;
  floatx4 acc[4][4] = {};
  float pb[8];
  // prologue: A k-step 0 -> buf0; B regs for k-step 0
  gload_lds16(Ab + (long)ra * 256 + sc, wA0);
  gload_lds16(Ab + (long)(ra + 128) * 256 + sc, wA0 + 128 * 32);
#pragma unroll
  for (int i = 0; i < 4; ++i) {
    pb[i]     = Xb[(long)erp * 4096 + n0 + 32 * i];
    pb[4 + i] = Xb[(long)(erp + 1) * 4096 + n0 + 32 * i];
  }
  for (int s = 0; s < 8; ++s) {
    const int kk = s * 32;
    const u16* curA = lA[s & 1];
    __syncthreads();  // drains gloads into buf[s&1] + pb loads (vmcnt 0)
    // stage lB: pair-pack (erp, erp+1) rows, XOR e-block swizzle
#pragma unroll
    for (int i = 0; i < 4; ++i) {
      const int nl = n0 + 32 * i;
      const int sb = (erp >> 3) ^ ((nl >> 4) & 3);
      *(unsigned int*)(lB + nl * 40 + sb * 8 + (erp & 7)) =
          cvt_pk_bf16(pb[i], pb[4 + i]);
    }
    __syncthreads();  // lB visible
    if (s < 7) {      // next-step prefetch overlaps MFMA phase
      const int k2 = kk + 32;
      u16* nA = (s & 1) ? wA0 : wA1;
      gload_lds16(Ab + (long)ra * 256 + k2 + sc, nA);
      gload_lds16(Ab + (long)(ra + 128) * 256 + k2 + sc, nA + 128 * 32);
#pragma unroll
      for (int i = 0; i < 4; ++i) {
        pb[i]     = Xb[(long)(k2 + erp) * 4096 + n0 + 32 * i];
        pb[4 + i] = Xb[(long)(k2 + erp + 1) * 4096 + n0 + 32 * i];
      }
    }
    short8 af[4];
#pragma unroll
    for (int i = 0; i < 4; ++i)
      af[i] = *(const short8*)(curA + (wm + i * 16 + l16) * 32 + rqA);
#pragma unroll
    for (int j = 0; j < 4; ++j) {
      const int n = wn + j * 16 + l16;
      const int rb = quad ^ ((n >> 4) & 3);
      const short8 bf = *(const short8*)(lB + n * 40 + rb * 8);
#pragma unroll
      for (int i = 0; i < 4; ++i)
        acc[i][j] = __builtin_amdgcn_mfma_f32_16x16x32_bf16(af[i], bf, acc[i][j], 0, 0, 0);
    }
  }
  const long obase = (long)b * 1048576;
#pragma unroll
  for (int i = 0; i < 4; ++i) {
    const int mb = wm + i * 16 + quad * 4;
#pragma unroll
    for (int j = 0; j < 4; ++j) {
      const int n = tn * 128 + wn + j * 16 + l16;
#pragma unroll
      for (int r = 0; r < 4; ++r)
        out[obase + (long)(mb + r) * 4096 + n] = acc[i][j][r] + bb[b * 256 + mb + r];
    }
  }
}

// ---------------- bias prep: s2[b][a]=w2[a,:]·xsum[b], s3 likewise --------
__global__ __launch_bounds__(512) void bias_prep_kernel(
    const float* __restrict__ w2, const float* __restrict__ w3,
    const float* __restrict__ xsum, float* __restrict__ S2, float* __restrict__ S3) {
  __shared__ float xs[256];
  const int b = blockIdx.x, t = threadIdx.x;
  if (t < 256) xs[t] = xsum[b * 256 + t];
  __syncthreads();
  const float* wm = (t < 256) ? w2 : w3;
  const int a = t & 255;
  float s = 0.f;
#pragma unroll 4
  for (int c = 0; c < 256; ++c) s += wm[a * 256 + c] * xs[c];
  if (t < 256) S2[b * 256 + a] = s;
  else         S3[b * 256 + a] = s;
}

// ---------------- softmax pass1: per-block (max, sumexp) ------------------
__global__ __launch_bounds__(256) void softmax_pass1(
    const float* __restrict__ Lt, const float* __restrict__ S2, const float* __restrict__ S3,
    const float* __restrict__ b2, const float* __restrict__ b3,
    float* __restrict__ bm, float* __restrict__ bs) {
  __shared__ float ls2[256], lb2[256];
  __shared__ float redm[4], reds[4];
  const int b = blockIdx.y, blk = blockIdx.x, t = threadIdx.x;
  ls2[t] = S2[b * 256 + t];
  lb2[t] = b2[t];
  __syncthreads();
  const int fw0 = blk * 2048 + t * 8;
  const int d = fw0 >> 8, a0 = fw0 & 255;
  const float c1 = b3[d];
  const float c0 = S3[b * 256 + d] + 4096.f * c1;
  const long base = (long)b * 65536 + fw0;
  float4 v0 = *(const float4*)(Lt + base);
  float4 v1 = *(const float4*)(Lt + base + 4);
  float v[8] = {v0.x, v0.y, v0.z, v0.w, v1.x, v1.y, v1.z, v1.w};
  float m = -3.4e38f;
#pragma unroll
  for (int i = 0; i < 8; ++i) {
    v[i] += lb2[a0 + i] * c0 + c1 * ls2[a0 + i];
    m = fmaxf(m, v[i]);
  }
  for (int o = 32; o; o >>= 1) m = fmaxf(m, __shfl_xor(m, o));
  const int wid = t >> 6, lane = t & 63;
  if (lane == 0) redm[wid] = m;
  __syncthreads();
  const float bmax = fmaxf(fmaxf(redm[0], redm[1]), fmaxf(redm[2], redm[3]));
  float s = 0.f;
#pragma unroll
  for (int i = 0; i < 8; ++i) s += __expf(v[i] - bmax);
  for (int o = 32; o; o >>= 1) s += __shfl_xor(s, o);
  if (lane == 0) reds[wid] = s;
  __syncthreads();
  if (t == 0) {
    bm[b * 32 + blk] = bmax;
    bs[b * 32 + blk] = reds[0] + reds[1] + reds[2] + reds[3];
  }
}

// -- softmax pass3: inline combine + write WT bf16 + fused bb[d]=WT·b1 ------
__global__ __launch_bounds__(256) void softmax_pass3(
    const float* __restrict__ Lt, const float* __restrict__ S2, const float* __restrict__ S3,
    const float* __restrict__ b2, const float* __restrict__ b3,
    const float* __restrict__ bm, const float* __restrict__ bs,
    const float* __restrict__ b1, u16* __restrict__ WTh, float* __restrict__ bb) {
  __shared__ float ls2[256], lb2[256], lb1[256];
  __shared__ float sM, sInv;
  const int b = blockIdx.y, blk = blockIdx.x, t = threadIdx.x;
  if (t < 64) {  // combine 32 block pairs (wave 0 only)
    const float m = (t < 32) ? bm[b * 32 + t] : -3.4e38f;
    float s = (t < 32) ? bs[b * 32 + t] : 0.f;
    float M = m;
    for (int o = 32; o; o >>= 1) M = fmaxf(M, __shfl_xor(M, o));
    s *= __expf(m - M);
    for (int o = 32; o; o >>= 1) s += __shfl_xor(s, o);
    if (t == 0) { sM = M; sInv = 1.0f / s; }
  }
  ls2[t] = S2[b * 256 + t];
  lb2[t] = b2[t];
  lb1[t] = b1[t];
  __syncthreads();
  const float M = sM, inv = sInv;
  const int fw0 = blk * 2048 + t * 8;
  const int d = fw0 >> 8, a0 = fw0 & 255;
  const float c1 = b3[d];
  const float c0 = S3[b * 256 + d] + 4096.f * c1;
  const long base = (long)b * 65536 + fw0;
  float4 v0 = *(const float4*)(Lt + base);
  float4 v1 = *(const float4*)(Lt + base + 4);
  float v[8] = {v0.x, v0.y, v0.z, v0.w, v1.x, v1.y, v1.z, v1.w};
  union { u16 h[8]; uint4 q; } o;
  float bsum = 0.f;
#pragma unroll
  for (int i = 0; i < 8; ++i) {
    const float vv = v[i] + lb2[a0 + i] * c0 + c1 * ls2[a0 + i];
    const float w = __expf(vv - M) * inv;
    o.h[i] = f2b(w);
    bsum += w * lb1[a0 + i];
  }
  *(uint4*)(WTh + base) = o.q;
  // row d spans 32 consecutive threads
  for (int off = 16; off; off >>= 1) bsum += __shfl_xor(bsum, off);
  if ((t & 31) == 0) bb[b * 256 + d] = bsum;
}

extern "C" void kernel_launch(void* const* d_in, const int* in_sizes, int n_in,
                              void* d_out, int out_size, void* d_ws, size_t ws_size,
                              hipStream_t stream) {
  const float* x  = (const float*)d_in[0];
  const float* w1 = (const float*)d_in[1];
  const float* b1 = (const float*)d_in[2];
  const float* w2 = (const float*)d_in[3];
  const float* b2 = (const float*)d_in[4];
  const float* w3 = (const float*)d_in[5];
  const float* b3 = (const float*)d_in[6];
  float* out = (float*)d_out;

  char* ws = (char*)d_ws;
  size_t off = 0;
  auto alloc = [&](size_t bytes) {
    void* p = ws + off;
    off += (bytes + 255) & ~(size_t)255;
    return p;
  };
  float* Gp = (float*)alloc(16ull * 16 * 65536 * 4);   // 64 MiB split-K partials
  float* xsum = (float*)alloc(16 * 256 * 4);
  u16* Gh   = (u16*)alloc(16ull * 65536 * 2);
  u16* Gl   = (u16*)alloc(16ull * 65536 * 2);
  u16* T3h  = (u16*)alloc(16ull * 65536 * 2);
  u16* T3l  = (u16*)alloc(16ull * 65536 * 2);
  float* Lb = (float*)alloc(16ull * 65536 * 4);        // Lt[d][a]
  u16* WTh  = (u16*)alloc(16ull * 65536 * 2);
  u16* Mh   = (u16*)alloc(16ull * 65536 * 2);
  u16* W1Th = (u16*)alloc(65536 * 2);
  u16* W2h  = (u16*)alloc(65536 * 2);
  u16* W2l  = (u16*)alloc(65536 * 2);
  u16* W3h  = (u16*)alloc(65536 * 2);
  u16* W3l  = (u16*)alloc(65536 * 2);
  float* S2   = (float*)alloc(16 * 256 * 4);
  float* S3   = (float*)alloc(16 * 256 * 4);
  float* bmx  = (float*)alloc(16 * 32 * 4);
  float* bsx  = (float*)alloc(16 * 32 * 4);
  float* bb   = (float*)alloc(16 * 256 * 4);

  prep_w_kernel<<<577, 256, 0, stream>>>(w1, w2, w3, W1Th, W2h, W2l, W3h, W3l, xsum);

  // Gram partials: 16 batches x 16 splits x 2 m-halves (xsum fused, mh==0).
  gram_kernel<<<512, 512, 0, stream>>>(x, Gp, xsum);
  reduce_g_kernel<<<1024, 256, 0, stream>>>(Gp, Gh, Gl);

  // T3 = W3 * G (G symmetric -> TN ok). 64x64 tiles, 256 blocks.
  gemm_small<true, 1><<<dim3(16, 1, 16), 256, 0, stream>>>(
      W3h, W3l, Gh, Gl, 0, 65536, 65536, nullptr, T3h, T3l);
  // Lt = T3 * W2^T  ->  Lt[d][a] = logits[a][d].
  gemm_small<true, 0><<<dim3(16, 1, 16), 256, 0, stream>>>(
      T3h, T3l, W2h, W2l, 65536, 0, 65536, Lb, nullptr, nullptr);

  // softmax: bias prep + pass1 + fused combine/write/bb pass3
  bias_prep_kernel<<<16, 512, 0, stream>>>(w2, w3, xsum, S2, S3);
  softmax_pass1<<<dim3(32, 16), 256, 0, stream>>>(Lb, S2, S3, b2, b3, bmx, bsx);
  softmax_pass3<<<dim3(32, 16), 256, 0, stream>>>(Lb, S2, S3, b2, b3, bmx, bsx,
                                                  b1, WTh, bb);

  // out-chain: Mh = WT*W1T (bf16), out = Mh*X^T + bb
  gemm_small<false, 2><<<dim3(16, 1, 16), 256, 0, stream>>>(
      WTh, nullptr, W1Th, nullptr, 65536, 0, 65536, nullptr, Mh, nullptr);
  gemm_out<<<dim3(32, 1, 16), 512, 0, stream>>>(Mh, x, bb, out);
}

// Round 8
// 213.188 us; speedup vs baseline: 1.2515x; 1.0185x over previous
//
#include <hip/hip_runtime.h>

// GlobalChannelAttention: B=16, C=256, H*W=4096
//
// Pipeline (TN-form GEMMs: C[M,N] = sum_k A[m][k]*B[n][k], K contiguous):
//   1. prep_w: w1 -> W1Th (bf16 transposed), w2/w3 -> hi/lo bf16, zero xsum
//   2. gram: G[b] = X X^T from raw x f32 (hi/lo in SEPARATE LDS slabs, 3
//      MFMAs hh+hl+lh). HALF-M blocks: grid 16b x 16splits x 2mhalf.
//      Per-split k-step STAGGER (ph = s&7) decorrelates HBM bursts.
//   3. reduce_g: sum 16 partials -> Gh/Gl bf16 (float4-vectorized stream).
//      T3 = W3*G (G symmetric); Lt = T3*W2^T (EPI=3: epilogue also computes
//      per-tile biased max/sumexp partials -> softmax pass1 ELIMINATED).
//   4. softmax pass3: combine 16 tile partials + write WT bf16 + fused
//      bb[d] = sum_c WT[d][c]*b1[c].
//   5. Mh = WT*W1T (bf16); out = Mh*X^T + bb, 256x128 tiles, 512 thr.
//
// Precision: logit chain bf16 hi/lo x3 (err ~2^-17 rel); out chain plain bf16.
// R7: atomic-f32 Gram epilogue regressed (16-way same-address L2 contention).
// R8: k-interleaved hi/lo loses hi*lo cross terms -> accuracy fail.
// R9: 128-VGPR acc forced fragment rematerialization -> LDS-read bound.
// R10: separate xsum_kernel re-read 64MB of x -- folded back into gram.
// R11: gram 16 k-splits, 64KiB LDS XOR-swizzle, cvt_pk staging. 46->41us,
//     0 bank conflicts (verified R5).
// R12/R13: launch_bounds(512,4) = 4 BLOCKS/CU -> 64-VGPR cap -> spill.
// R14: (512,2): spill gone; lB-write conflicts found.
// R15: gemm_out gload_lds dbuf A + conflict-free lB; left top-5.
// R16: gemm_small full-panel LDS single-barrier; left top-5. Total 217:
//     gram 41 (2x of 21us BW floor, latency-exposed) + fill 40.5 (harness).
// R17: (a) gram k-step stagger ph=s&7 -- zero-VGPR-cost HBM burst
//     decorrelation (mh pairs keep same phase -> L2 dedup preserved; f32
//     reorder within tolerance). (b) softmax pass1 fused into gemm#2
//     epilogue (EPI=3); pass3 combine 32->16; bias_prep reordered before
//     gemm#2. 10 -> 9 launches, -4MB traffic.
// R18 (this round): R17 bench never ran (container infra failure, 2nd
//     occurrence; R2 precedent resolved by resubmission). Audit found no
//     OOB/sync hazard in the R17 diff; resubmitting unchanged.

typedef unsigned short u16;
typedef __attribute__((ext_vector_type(8))) short short8;
typedef __attribute__((ext_vector_type(4))) float floatx4;

__device__ __forceinline__ u16 f2b(float f) {
  union { float f; unsigned int u; } v; v.f = f;
  unsigned int u = v.u;
  return (u16)((u + 0x7fffu + ((u >> 16) & 1u)) >> 16);  // RNE
}
__device__ __forceinline__ float b2f(u16 h) {
  union { unsigned int u; float f; } v; v.u = ((unsigned int)h) << 16;
  return v.f;
}
// HW packed f32->bf16 (RNE), lo -> bits[15:0], hi -> bits[31:16].
__device__ __forceinline__ unsigned int cvt_pk_bf16(float lo, float hi) {
  unsigned int r;
  asm("v_cvt_pk_bf16_f32 %0, %1, %2" : "=v"(r) : "v"(lo), "v"(hi));
  return r;
}
// async global->LDS, 16B per lane. LDS dest = wave-uniform base + lane*16.
__device__ __forceinline__ void gload_lds16(const u16* g, u16* l) {
  __builtin_amdgcn_global_load_lds(
      (const __attribute__((address_space(1))) unsigned int*)(const void*)g,
      (__attribute__((address_space(3))) unsigned int*)(void*)l, 16, 0, 0);
}

// ------- merged W prep: transpose w1 + split w2/w3 + zero xsum -------------
__global__ __launch_bounds__(256) void prep_w_kernel(
    const float* __restrict__ w1, const float* __restrict__ w2, const float* __restrict__ w3,
    u16* __restrict__ W1Th, u16* __restrict__ W2h, u16* __restrict__ W2l,
    u16* __restrict__ W3h, u16* __restrict__ W3l, float* __restrict__ xsum) {
  const int blk = blockIdx.x, t = threadIdx.x;
  if (blk == 576) {  // zero xsum (16*256 f32)
#pragma unroll
    for (int i = 0; i < 16; ++i) xsum[t + i * 256] = 0.f;
    return;
  }
  if (blk < 64) {  // W1Th[e][c] = w1[c][e]
    __shared__ float tile[32][33];
    const int e0 = (blk & 7) * 32, c0 = (blk >> 3) * 32;
    const int tx = t & 31, ty = t >> 5;
#pragma unroll
    for (int i = 0; i < 4; ++i)
      tile[ty + i * 8][tx] = w1[(c0 + ty + i * 8) * 256 + e0 + tx];
    __syncthreads();
#pragma unroll
    for (int i = 0; i < 4; ++i)
      W1Th[(e0 + ty + i * 8) * 256 + c0 + tx] = f2b(tile[tx][ty + i * 8]);
  } else {
    const int i = (blk - 64) * 256 + t;  // 0..131071
    const int e = i & 0xffff;
    const float f = (i >> 16) ? w3[e] : w2[e];
    u16 h = f2b(f);
    if (i >> 16) { W3h[e] = h; W3l[e] = f2b(f - b2f(h)); }
    else         { W2h[e] = h; W2l[e] = f2b(f - b2f(h)); }
  }
}

// ---- stage 8 f32 -> hi/lo bf16 LDS (one uint4 each) + running sum --------
__device__ __forceinline__ void stage8(const float4 a, const float4 b,
                                       u16* dH, u16* dL, float& xa) {
  const float f[8] = {a.x, a.y, a.z, a.w, b.x, b.y, b.z, b.w};
  union { unsigned int w[4]; uint4 q; } uh, ul;
#pragma unroll
  for (int i = 0; i < 4; ++i) {
    const unsigned int h = cvt_pk_bf16(f[2 * i], f[2 * i + 1]);
    uh.w[i] = h;
    union { unsigned int u; float ff; } h0, h1;
    h0.u = h << 16;            // bf16 of f[2i] back to f32
    h1.u = h & 0xffff0000u;    // bf16 of f[2i+1] back to f32
    ul.w[i] = cvt_pk_bf16(f[2 * i] - h0.ff, f[2 * i + 1] - h1.ff);
    xa += f[2 * i] + f[2 * i + 1];
  }
  *(uint4*)dH = uh.q;
  *(uint4*)dL = ul.q;
}

// ---------------- Gram: half-M blocks, hoisted fragments -------------------
// grid = 16b x 16s x 2mh. 512 thr / 8 waves, wave tile 64x64, k-chunk 256.
// LDS: row r = 64B = 4x16B slots; slot q ^ ((r>>1)&3); both phases bank-free
// (measured 0 conflicts). 64 KiB -> 2 blocks/CU. k-step order rotated by
// ph = s&7 (mh pairs share phase -> L2 dedup kept; f32 reorder only).
__global__ __launch_bounds__(512, 4) void gram_kernel(
    const float* __restrict__ x, float* __restrict__ Gp, float* __restrict__ xsum) {
  __shared__ u16 lH[2][256 * 32], lL[2][256 * 32];  // 64 KB total
  const int b = blockIdx.x >> 5, s = (blockIdx.x >> 1) & 15, mh = blockIdx.x & 1;
  const float* Xb = x + (long)b * 1048576 + s * 256;
  const int t = threadIdx.x;
  const int lane = t & 63, wave = t >> 6;
  const int quad = lane >> 4, l16 = lane & 15;
  const int wml = (wave & 1) * 64 + mh * 128;  // A rows in slab
  const int wn = (wave >> 1) * 64;             // B rows
  const int r0 = t >> 2, qc = (t & 3) * 8;
  const int r1 = r0 + 128;                     // (r1>>1)&3 == (r0>>1)&3
  const int wq = (((t & 3) ^ ((r0 >> 1) & 3))) * 8;  // swizzled write slot
  const int rq = ((quad ^ ((l16 >> 1) & 3))) * 8;    // swizzled read slot
  const int ph = s & 7;  // k-step phase stagger
  floatx4 acc[4][4] = {};
  float xa0 = 0.f, xa1 = 0.f;  // per-row running sums (rows r0, r1)
  float4 p[4];
  {
    const long k0 = ph * 32;
    p[0] = *(const float4*)(Xb + (long)r0 * 4096 + k0 + qc);
    p[1] = *(const float4*)(Xb + (long)r0 * 4096 + k0 + qc + 4);
    p[2] = *(const float4*)(Xb + (long)r1 * 4096 + k0 + qc);
    p[3] = *(const float4*)(Xb + (long)r1 * 4096 + k0 + qc + 4);
  }
  stage8(p[0], p[1], lH[0] + r0 * 32 + wq, lL[0] + r0 * 32 + wq, xa0);
  stage8(p[2], p[3], lH[0] + r1 * 32 + wq, lL[0] + r1 * 32 + wq, xa1);
  __syncthreads();
  for (int kb = 0; kb < 8; ++kb) {
    const int cur = kb & 1, nxt = cur ^ 1;
    if (kb < 7) {  // issue next tile's loads; waitcnt lands after MFMA block
      const long kk = (long)(((kb + 1 + ph) & 7) * 32);
      p[0] = *(const float4*)(Xb + (long)r0 * 4096 + kk + qc);
      p[1] = *(const float4*)(Xb + (long)r0 * 4096 + kk + qc + 4);
      p[2] = *(const float4*)(Xb + (long)r1 * 4096 + kk + qc);
      p[3] = *(const float4*)(Xb + (long)r1 * 4096 + kk + qc + 4);
    }
    const u16* cH = lH[cur];
    const u16* cL = lL[cur];
    short8 ah[4], al[4];
#pragma unroll
    for (int i = 0; i < 4; ++i) {
      ah[i] = *(const short8*)(cH + (wml + i * 16 + l16) * 32 + rq);
      al[i] = *(const short8*)(cL + (wml + i * 16 + l16) * 32 + rq);
    }
#pragma unroll
    for (int j = 0; j < 4; ++j) {
      const short8 bh = *(const short8*)(cH + (wn + j * 16 + l16) * 32 + rq);
      const short8 bl = *(const short8*)(cL + (wn + j * 16 + l16) * 32 + rq);
#pragma unroll
      for (int i = 0; i < 4; ++i) {
        acc[i][j] = __builtin_amdgcn_mfma_f32_16x16x32_bf16(ah[i], bh, acc[i][j], 0, 0, 0);
        acc[i][j] = __builtin_amdgcn_mfma_f32_16x16x32_bf16(ah[i], bl, acc[i][j], 0, 0, 0);
        acc[i][j] = __builtin_amdgcn_mfma_f32_16x16x32_bf16(al[i], bh, acc[i][j], 0, 0, 0);
      }
    }
    if (kb < 7) {
      stage8(p[0], p[1], lH[nxt] + r0 * 32 + wq, lL[nxt] + r0 * 32 + wq, xa0);
      stage8(p[2], p[3], lH[nxt] + r1 * 32 + wq, lL[nxt] + r1 * 32 + wq, xa1);
    }
    __syncthreads();
  }
  if (mh == 0) {
    float v = xa0;
    v += __shfl_xor(v, 1);
    v += __shfl_xor(v, 2);
    if ((t & 3) == 0) atomicAdd(&xsum[b * 256 + r0], v);
    v = xa1;
    v += __shfl_xor(v, 1);
    v += __shfl_xor(v, 2);
    if ((t & 3) == 0) atomicAdd(&xsum[b * 256 + r1], v);
  }
  float* G = Gp + ((long)b * 16 + s) * 65536;
#pragma unroll
  for (int i = 0; i < 4; ++i) {
    const int row0 = wml + i * 16 + quad * 4;
#pragma unroll
    for (int j = 0; j < 4; ++j) {
      const int col = wn + j * 16 + l16;
#pragma unroll
      for (int r = 0; r < 4; ++r)
        G[(long)(row0 + r) * 256 + col] = acc[i][j][r];
    }
  }
}

// ------ Gram split-K reduction + hi/lo split (16 splits, float4 stream) ----
__global__ __launch_bounds__(256) void reduce_g_kernel(
    const float* __restrict__ Gp, u16* __restrict__ Gh, u16* __restrict__ Gl) {
  const long e = ((long)blockIdx.x * 256 + threadIdx.x) * 4;  // elem base
  const long base = ((e >> 16) << 20) + (e & 65535);          // b*16*65536 + idx
  float4 s = {0.f, 0.f, 0.f, 0.f};
#pragma unroll
  for (int i = 0; i < 16; ++i) {
    const float4 v = *(const float4*)(Gp + base + (long)i * 65536);
    s.x += v.x; s.y += v.y; s.z += v.z; s.w += v.w;
  }
  union { u16 h[4]; uint2 q; } oh, ol;
  const float sv[4] = {s.x, s.y, s.z, s.w};
#pragma unroll
  for (int c = 0; c < 4; ++c) {
    const u16 h = f2b(sv[c]);
    oh.h[c] = h;
    ol.h[c] = f2b(sv[c] - b2f(h));
  }
  *(uint2*)(Gh + e) = oh.q;
  *(uint2*)(Gl + e) = ol.q;
}

// ------- small 256x256x256 TN GEMM: full-panel LDS, 64x64 tiles ------------
// Full A(64x256) + B(64x256) hi(/lo) panels staged ONCE into padded LDS
// ([64][264] u16, 528B row stride -> conflict-free), one barrier, then 8
// barrier-free k-steps. Grid 256 = 1 block/CU. EPI: 0=f32, 1=bf16 hi/lo,
// 2=bf16 hi, 3=f32 + fused softmax-pass1 stats (biased per-tile max/sumexp
// -> bm/bs[b*16+blk]; raw value still stored to outF).
template <bool X3, int EPI>
__global__ __launch_bounds__(256) void gemm_small(
    const u16* __restrict__ Ah, const u16* __restrict__ Al,
    const u16* __restrict__ Bh, const u16* __restrict__ Bl,
    long aBatch, long bBatch, long oBatch,
    float* __restrict__ outF, u16* __restrict__ outH, u16* __restrict__ outL,
    const float* __restrict__ S2, const float* __restrict__ S3,
    const float* __restrict__ b2v, const float* __restrict__ b3v,
    float* __restrict__ bm, float* __restrict__ bs) {
  constexpr int LW = 264;  // row stride in elems (528 B)
  __shared__ u16 smem[(X3 ? 4 : 2) * 64 * LW];
  __shared__ float rm[4], rs[4];  // EPI3 block-reduce scratch
  u16* lAh = smem;
  u16* lBh = smem + 64 * LW;
  u16* lAl = X3 ? (smem + 2 * 64 * LW) : nullptr;
  u16* lBl = X3 ? (smem + 3 * 64 * LW) : nullptr;
  const int b = blockIdx.z;
  const int tm = blockIdx.x & 3, tn = blockIdx.x >> 2;  // 4x4 tiles of 64
  const u16* Ahb = Ah + (long)b * aBatch + (long)tm * 64 * 256;
  const u16* Bhb = Bh + (long)b * bBatch + (long)tn * 64 * 256;
  const int t = threadIdx.x;
  const int lane = t & 63, wave = t >> 6;
  const int quad = lane >> 4, l16 = lane & 15;
  const int wm = (wave & 1) * 32, wn = (wave >> 1) * 32;
  const int r = t >> 2, c4 = t & 3;  // staging: row r, slots c4+4j (16B each)
  {
    uint4 tmp[8];
#pragma unroll
    for (int j = 0; j < 8; ++j)
      tmp[j] = *(const uint4*)(Ahb + (long)r * 256 + (c4 + 4 * j) * 8);
#pragma unroll
    for (int j = 0; j < 8; ++j)
      *(uint4*)(lAh + r * LW + (c4 + 4 * j) * 8) = tmp[j];
#pragma unroll
    for (int j = 0; j < 8; ++j)
      tmp[j] = *(const uint4*)(Bhb + (long)r * 256 + (c4 + 4 * j) * 8);
#pragma unroll
    for (int j = 0; j < 8; ++j)
      *(uint4*)(lBh + r * LW + (c4 + 4 * j) * 8) = tmp[j];
    if (X3) {
      const u16* Alb = Al + (long)b * aBatch + (long)tm * 64 * 256;
      const u16* Blb = Bl + (long)b * bBatch + (long)tn * 64 * 256;
#pragma unroll
      for (int j = 0; j < 8; ++j)
        tmp[j] = *(const uint4*)(Alb + (long)r * 256 + (c4 + 4 * j) * 8);
#pragma unroll
      for (int j = 0; j < 8; ++j)
        *(uint4*)(lAl + r * LW + (c4 + 4 * j) * 8) = tmp[j];
#pragma unroll
      for (int j = 0; j < 8; ++j)
        tmp[j] = *(const uint4*)(Blb + (long)r * 256 + (c4 + 4 * j) * 8);
#pragma unroll
      for (int j = 0; j < 8; ++j)
        *(uint4*)(lBl + r * LW + (c4 + 4 * j) * 8) = tmp[j];
    }
  }
  __syncthreads();  // the ONLY barrier in the GEMM body
  floatx4 acc[2][2] = {};
#pragma unroll
  for (int kk = 0; kk < 8; ++kk) {
    const int co = kk * 32 + quad * 8;
    short8 afh[2], bfh[2];
#pragma unroll
    for (int i = 0; i < 2; ++i) {
      afh[i] = *(const short8*)(lAh + (wm + i * 16 + l16) * LW + co);
      bfh[i] = *(const short8*)(lBh + (wn + i * 16 + l16) * LW + co);
    }
    if (X3) {
      short8 afl[2], bfl[2];
#pragma unroll
      for (int i = 0; i < 2; ++i) {
        afl[i] = *(const short8*)(lAl + (wm + i * 16 + l16) * LW + co);
        bfl[i] = *(const short8*)(lBl + (wn + i * 16 + l16) * LW + co);
      }
#pragma unroll
      for (int i = 0; i < 2; ++i)
#pragma unroll
        for (int j = 0; j < 2; ++j) {
          acc[i][j] = __builtin_amdgcn_mfma_f32_16x16x32_bf16(afh[i], bfh[j], acc[i][j], 0, 0, 0);
          acc[i][j] = __builtin_amdgcn_mfma_f32_16x16x32_bf16(afh[i], bfl[j], acc[i][j], 0, 0, 0);
          acc[i][j] = __builtin_amdgcn_mfma_f32_16x16x32_bf16(afl[i], bfh[j], acc[i][j], 0, 0, 0);
        }
    } else {
#pragma unroll
      for (int i = 0; i < 2; ++i)
#pragma unroll
        for (int j = 0; j < 2; ++j)
          acc[i][j] = __builtin_amdgcn_mfma_f32_16x16x32_bf16(afh[i], bfh[j], acc[i][j], 0, 0, 0);
    }
  }
  const long obase = (long)b * oBatch;
  if (EPI == 3) {
    // store raw Lt + fused pass1 stats on biased values
    float vals[2][2][4];
    float vmax = -3.4e38f;
#pragma unroll
    for (int i = 0; i < 2; ++i) {
      const int mb = tm * 64 + wm + i * 16 + quad * 4;
#pragma unroll
      for (int rr = 0; rr < 4; ++rr) {
        const int d = mb + rr;
        const float c1 = b3v[d];
        const float c0 = S3[b * 256 + d] + 4096.f * c1;
#pragma unroll
        for (int j = 0; j < 2; ++j) {
          const int a = tn * 64 + wn + j * 16 + l16;
          const float raw = acc[i][j][rr];
          const float vv = raw + b2v[a] * c0 + c1 * S2[b * 256 + a];
          vals[i][j][rr] = vv;
          vmax = fmaxf(vmax, vv);
          outF[obase + (long)d * 256 + a] = raw;
        }
      }
    }
    for (int o = 32; o; o >>= 1) vmax = fmaxf(vmax, __shfl_xor(vmax, o));
    if (lane == 0) rm[wave] = vmax;
    __syncthreads();
    const float bmax = fmaxf(fmaxf(rm[0], rm[1]), fmaxf(rm[2], rm[3]));
    float se = 0.f;
#pragma unroll
    for (int i = 0; i < 2; ++i)
#pragma unroll
      for (int j = 0; j < 2; ++j)
#pragma unroll
        for (int rr = 0; rr < 4; ++rr) se += __expf(vals[i][j][rr] - bmax);
    for (int o = 32; o; o >>= 1) se += __shfl_xor(se, o);
    if (lane == 0) rs[wave] = se;
    __syncthreads();
    if (t == 0) {
      bm[b * 16 + blockIdx.x] = bmax;
      bs[b * 16 + blockIdx.x] = rs[0] + rs[1] + rs[2] + rs[3];
    }
    return;
  }
#pragma unroll
  for (int i = 0; i < 2; ++i) {
    const int mb = tm * 64 + wm + i * 16 + quad * 4;
#pragma unroll
    for (int j = 0; j < 2; ++j) {
      const int n = tn * 64 + wn + j * 16 + l16;
#pragma unroll
      for (int rr = 0; rr < 4; ++rr) {
        const float v = acc[i][j][rr];
        const long idx = obase + (long)(mb + rr) * 256 + n;
        if (EPI == 0) {
          outF[idx] = v;
        } else if (EPI == 1) {
          u16 h = f2b(v);
          outH[idx] = h;
          outL[idx] = f2b(v - b2f(h));
        } else {
          outH[idx] = f2b(v);
        }
      }
    }
  }
}

// ------------- out = Mh * X^T + bb : 256x128 per block, 8 waves ------------
// A (Mh bf16): global_load_lds width-16, double-buffered, rows 64B (LR=32),
// XOR slot q^((r>>1)&3) applied to per-lane GLOBAL source col + read slot.
// B (x f32): 8 coalesced scalar dwords, cvt_pk pair-pack into lB (LR=40);
// lane t writes nl=(t&31)+32i (write phase conflict-free).
__global__ __launch_bounds__(512, 2) void gemm_out(
    const u16* __restrict__ Mh, const float* __restrict__ x,
    const float* __restrict__ bb, float* __restrict__ out) {
  __shared__ u16 lA[2][256 * 32];  // 2 x 16 KB
  __shared__ u16 lB[128 * 40];     // 10 KB
  const int b = blockIdx.z;
  const int tn = blockIdx.x;  // 0..31
  const u16* Ab = Mh + (long)b * 65536;
  const float* Xb = x + (long)b * 1048576 + tn * 128;
  const int t = threadIdx.x;
  const int lane = t & 63, wave = t >> 6;
  const int quad = lane >> 4, l16 = lane & 15;
  const int wm = (wave & 3) * 64;     // 4 m-waves
  const int wn = (wave >> 2) * 64;    // 2 n-waves
  const int erp = (t >> 5) * 2;       // e-row pair base 0..30
  const int n0 = t & 31;              // B col base (cols n0+32i)
  const int ra = t >> 2;              // A row
  const int sc = ((t & 3) ^ ((t >> 3) & 3)) * 8;   // pre-swizzled A src col
  const int rqA = (quad ^ ((l16 >> 1) & 3)) * 8;   // A read slot
  u16* wA0 = &lA[0][0] + wave * 16 * 32;           // wave-uniform LDS bases
  u16* wA1 = &lA[1][0] + wave * 16 * 32;
  floatx4 acc[4][4] = {};
  float pb[8];
  gload_lds16(Ab + (long)ra * 256 + sc, wA0);
  gload_lds16(Ab + (long)(ra + 128) * 256 + sc, wA0 + 128 * 32);
#pragma unroll
  for (int i = 0; i < 4; ++i) {
    pb[i]     = Xb[(long)erp * 4096 + n0 + 32 * i];
    pb[4 + i] = Xb[(long)(erp + 1) * 4096 + n0 + 32 * i];
  }
  for (int s = 0; s < 8; ++s) {
    const int kk = s * 32;
    const u16* curA = lA[s & 1];
    __syncthreads();  // drains gloads into buf[s&1] + pb loads (vmcnt 0)
#pragma unroll
    for (int i = 0; i < 4; ++i) {
      const int nl = n0 + 32 * i;
      const int sb = (erp >> 3) ^ ((nl >> 4) & 3);
      *(unsigned int*)(lB + nl * 40 + sb * 8 + (erp & 7)) =
          cvt_pk_bf16(pb[i], pb[4 + i]);
    }
    __syncthreads();  // lB visible
    if (s < 7) {      // next-step prefetch overlaps MFMA phase
      const int k2 = kk + 32;
      u16* nA = (s & 1) ? wA0 : wA1;
      gload_lds16(Ab + (long)ra * 256 + k2 + sc, nA);
      gload_lds16(Ab + (long)(ra + 128) * 256 + k2 + sc, nA + 128 * 32);
#pragma unroll
      for (int i = 0; i < 4; ++i) {
        pb[i]     = Xb[(long)(k2 + erp) * 4096 + n0 + 32 * i];
        pb[4 + i] = Xb[(long)(k2 + erp + 1) * 4096 + n0 + 32 * i];
      }
    }
    short8 af[4];
#pragma unroll
    for (int i = 0; i < 4; ++i)
      af[i] = *(const short8*)(curA + (wm + i * 16 + l16) * 32 + rqA);
#pragma unroll
    for (int j = 0; j < 4; ++j) {
      const int n = wn + j * 16 + l16;
      const int rb = quad ^ ((n >> 4) & 3);
      const short8 bf = *(const short8*)(lB + n * 40 + rb * 8);
#pragma unroll
      for (int i = 0; i < 4; ++i)
        acc[i][j] = __builtin_amdgcn_mfma_f32_16x16x32_bf16(af[i], bf, acc[i][j], 0, 0, 0);
    }
  }
  const long obase = (long)b * 1048576;
#pragma unroll
  for (int i = 0; i < 4; ++i) {
    const int mb = wm + i * 16 + quad * 4;
#pragma unroll
    for (int j = 0; j < 4; ++j) {
      const int n = tn * 128 + wn + j * 16 + l16;
#pragma unroll
      for (int r = 0; r < 4; ++r)
        out[obase + (long)(mb + r) * 4096 + n] = acc[i][j][r] + bb[b * 256 + mb + r];
    }
  }
}

// ---------------- bias prep: s2[b][a]=w2[a,:]·xsum[b], s3 likewise --------
__global__ __launch_bounds__(512) void bias_prep_kernel(
    const float* __restrict__ w2, const float* __restrict__ w3,
    const float* __restrict__ xsum, float* __restrict__ S2, float* __restrict__ S3) {
  __shared__ float xs[256];
  const int b = blockIdx.x, t = threadIdx.x;
  if (t < 256) xs[t] = xsum[b * 256 + t];
  __syncthreads();
  const float* wm = (t < 256) ? w2 : w3;
  const int a = t & 255;
  float s = 0.f;
#pragma unroll 4
  for (int c = 0; c < 256; ++c) s += wm[a * 256 + c] * xs[c];
  if (t < 256) S2[b * 256 + a] = s;
  else         S3[b * 256 + a] = s;
}

// -- softmax pass3: combine 16 tile partials + write WT bf16 + bb[d]=WT·b1 --
__global__ __launch_bounds__(256) void softmax_pass3(
    const float* __restrict__ Lt, const float* __restrict__ S2, const float* __restrict__ S3,
    const float* __restrict__ b2, const float* __restrict__ b3,
    const float* __restrict__ bm, const float* __restrict__ bs,
    const float* __restrict__ b1, u16* __restrict__ WTh, float* __restrict__ bb) {
  __shared__ float ls2[256], lb2[256], lb1[256];
  __shared__ float sM, sInv;
  const int b = blockIdx.y, blk = blockIdx.x, t = threadIdx.x;
  if (t < 64) {  // combine 16 tile partials (wave 0 only)
    const float m = (t < 16) ? bm[b * 16 + t] : -3.4e38f;
    float s = (t < 16) ? bs[b * 16 + t] : 0.f;
    float M = m;
    for (int o = 32; o; o >>= 1) M = fmaxf(M, __shfl_xor(M, o));
    s *= __expf(m - M);
    for (int o = 32; o; o >>= 1) s += __shfl_xor(s, o);
    if (t == 0) { sM = M; sInv = 1.0f / s; }
  }
  ls2[t] = S2[b * 256 + t];
  lb2[t] = b2[t];
  lb1[t] = b1[t];
  __syncthreads();
  const float M = sM, inv = sInv;
  const int fw0 = blk * 2048 + t * 8;
  const int d = fw0 >> 8, a0 = fw0 & 255;
  const float c1 = b3[d];
  const float c0 = S3[b * 256 + d] + 4096.f * c1;
  const long base = (long)b * 65536 + fw0;
  float4 v0 = *(const float4*)(Lt + base);
  float4 v1 = *(const float4*)(Lt + base + 4);
  float v[8] = {v0.x, v0.y, v0.z, v0.w, v1.x, v1.y, v1.z, v1.w};
  union { u16 h[8]; uint4 q; } o;
  float bsum = 0.f;
#pragma unroll
  for (int i = 0; i < 8; ++i) {
    const float vv = v[i] + lb2[a0 + i] * c0 + c1 * ls2[a0 + i];
    const float w = __expf(vv - M) * inv;
    o.h[i] = f2b(w);
    bsum += w * lb1[a0 + i];
  }
  *(uint4*)(WTh + base) = o.q;
  // row d spans 32 consecutive threads
  for (int off = 16; off; off >>= 1) bsum += __shfl_xor(bsum, off);
  if ((t & 31) == 0) bb[b * 256 + d] = bsum;
}

extern "C" void kernel_launch(void* const* d_in, const int* in_sizes, int n_in,
                              void* d_out, int out_size, void* d_ws, size_t ws_size,
                              hipStream_t stream) {
  const float* x  = (const float*)d_in[0];
  const float* w1 = (const float*)d_in[1];
  const float* b1 = (const float*)d_in[2];
  const float* w2 = (const float*)d_in[3];
  const float* b2 = (const float*)d_in[4];
  const float* w3 = (const float*)d_in[5];
  const float* b3 = (const float*)d_in[6];
  float* out = (float*)d_out;

  char* ws = (char*)d_ws;
  size_t off = 0;
  auto alloc = [&](size_t bytes) {
    void* p = ws + off;
    off += (bytes + 255) & ~(size_t)255;
    return p;
  };
  float* Gp = (float*)alloc(16ull * 16 * 65536 * 4);   // 64 MiB split-K partials
  float* xsum = (float*)alloc(16 * 256 * 4);
  u16* Gh   = (u16*)alloc(16ull * 65536 * 2);
  u16* Gl   = (u16*)alloc(16ull * 65536 * 2);
  u16* T3h  = (u16*)alloc(16ull * 65536 * 2);
  u16* T3l  = (u16*)alloc(16ull * 65536 * 2);
  float* Lb = (float*)alloc(16ull * 65536 * 4);        // Lt[d][a]
  u16* WTh  = (u16*)alloc(16ull * 65536 * 2);
  u16* Mh   = (u16*)alloc(16ull * 65536 * 2);
  u16* W1Th = (u16*)alloc(65536 * 2);
  u16* W2h  = (u16*)alloc(65536 * 2);
  u16* W2l  = (u16*)alloc(65536 * 2);
  u16* W3h  = (u16*)alloc(65536 * 2);
  u16* W3l  = (u16*)alloc(65536 * 2);
  float* S2   = (float*)alloc(16 * 256 * 4);
  float* S3   = (float*)alloc(16 * 256 * 4);
  float* bmx  = (float*)alloc(16 * 16 * 4);
  float* bsx  = (float*)alloc(16 * 16 * 4);
  float* bb   = (float*)alloc(16 * 256 * 4);

  prep_w_kernel<<<577, 256, 0, stream>>>(w1, w2, w3, W1Th, W2h, W2l, W3h, W3l, xsum);

  // Gram partials: 16 batches x 16 splits x 2 m-halves (xsum fused, mh==0).
  gram_kernel<<<512, 512, 0, stream>>>(x, Gp, xsum);
  reduce_g_kernel<<<1024, 256, 0, stream>>>(Gp, Gh, Gl);

  // bias terms (needs xsum only) -- must precede the EPI=3 gemm below.
  bias_prep_kernel<<<16, 512, 0, stream>>>(w2, w3, xsum, S2, S3);

  // T3 = W3 * G (G symmetric -> TN ok). 64x64 tiles, 256 blocks.
  gemm_small<true, 1><<<dim3(16, 1, 16), 256, 0, stream>>>(
      W3h, W3l, Gh, Gl, 0, 65536, 65536, nullptr, T3h, T3l,
      nullptr, nullptr, nullptr, nullptr, nullptr, nullptr);
  // Lt = T3 * W2^T (raw) + fused softmax-pass1 stats (bm/bs per tile).
  gemm_small<true, 3><<<dim3(16, 1, 16), 256, 0, stream>>>(
      T3h, T3l, W2h, W2l, 65536, 0, 65536, Lb, nullptr, nullptr,
      S2, S3, b2, b3, bmx, bsx);

  // softmax: combine + write WT + fused bb
  softmax_pass3<<<dim3(32, 16), 256, 0, stream>>>(Lb, S2, S3, b2, b3, bmx, bsx,
                                                  b1, WTh, bb);

  // out-chain: Mh = WT*W1T (bf16), out = Mh*X^T + bb
  gemm_small<false, 2><<<dim3(16, 1, 16), 256, 0, stream>>>(
      WTh, nullptr, W1Th, nullptr, 65536, 0, 65536, nullptr, Mh, nullptr,
      nullptr, nullptr, nullptr, nullptr, nullptr, nullptr);
  gemm_out<<<dim3(32, 1, 16), 512, 0, stream>>>(Mh, x, bb, out);
}